// Round 1
// baseline (3819.334 us; speedup 1.0000x reference)
//
#include <hip/hip_runtime.h>

// ---------------------------------------------------------------------------
// AttentionBlock (SD-style): GN -> conv1x1 -> LN+MHA(self) -> LN+MHA(cross)
//                            -> LN+GeGLU FFN -> conv1x1 + long residual
// Round 0: fp32 correctness-first. B=8, C=640, HW=1024, H=8, DH=80, CTX 77x512.
// ---------------------------------------------------------------------------

#define DH 80

static __device__ __forceinline__ float gelu_f(float x) {
    return 0.5f * x * (1.0f + erff(x * 0.70710678118654752f));
}

// ------------------------- GroupNorm stats ---------------------------------
// One block per (n, g); group data is one contiguous span of 20*1024 floats.
__global__ __launch_bounds__(256) void gn_stats_k(const float* __restrict__ x,
                                                  float* __restrict__ stats) {
    const int ng = blockIdx.x;                       // n*32 + g
    const float4* base = (const float4*)(x + (size_t)ng * 20480);
    float s = 0.f, s2 = 0.f;
    for (int i = threadIdx.x; i < 5120; i += 256) {
        float4 v = base[i];
        s  += v.x + v.y + v.z + v.w;
        s2 += v.x*v.x + v.y*v.y + v.z*v.z + v.w*v.w;
    }
    for (int m = 1; m < 64; m <<= 1) { s += __shfl_xor(s, m); s2 += __shfl_xor(s2, m); }
    __shared__ float rs[4], rs2[4];
    if ((threadIdx.x & 63) == 0) { rs[threadIdx.x >> 6] = s; rs2[threadIdx.x >> 6] = s2; }
    __syncthreads();
    if (threadIdx.x == 0) {
        float ts = rs[0] + rs[1] + rs[2] + rs[3];
        float t2 = rs2[0] + rs2[1] + rs2[2] + rs2[3];
        float mu = ts * (1.f / 20480.f);
        float var = t2 * (1.f / 20480.f) - mu * mu;
        stats[ng * 2]     = mu;
        stats[ng * 2 + 1] = rsqrtf(var + 1e-6f);
    }
}

// ----------------- GroupNorm apply + transpose to token-major ---------------
// in x[n][c][p], out t[(n*1024+p)*640 + c]; 32x32 LDS tile transpose.
__global__ __launch_bounds__(256) void gn_apply_t_k(const float* __restrict__ x,
                                                    const float* __restrict__ stats,
                                                    const float* __restrict__ gs,
                                                    const float* __restrict__ gb,
                                                    float* __restrict__ out) {
    const int p0 = blockIdx.x * 32, c0 = blockIdx.y * 32, n = blockIdx.z;
    __shared__ float tile[32][33];
    const int t = threadIdx.x;
    {
        const int cl = t >> 5, pl = t & 31;
#pragma unroll
        for (int i = 0; i < 4; ++i) {
            int c = c0 + cl + i * 8;
            int g = c / 20;
            float mu = stats[(n * 32 + g) * 2];
            float rstd = stats[(n * 32 + g) * 2 + 1];
            float v = x[(size_t)n * 655360 + (size_t)c * 1024 + p0 + pl];
            tile[cl + i * 8][pl] = (v - mu) * rstd * gs[c] + gb[c];
        }
    }
    __syncthreads();
    {
        const int pl = t >> 5, cl = t & 31;
#pragma unroll
        for (int i = 0; i < 4; ++i) {
            int p = p0 + pl + i * 8;
            out[((size_t)n * 1024 + p) * 640 + c0 + cl] = tile[cl][pl + i * 8];
        }
    }
}

// --------------------------- LayerNorm (wave/row) ---------------------------
__global__ __launch_bounds__(256) void ln_k(const float* __restrict__ x,
                                            const float* __restrict__ g,
                                            const float* __restrict__ b,
                                            float* __restrict__ o) {
    const int row = blockIdx.x * 4 + (threadIdx.x >> 6);
    const int lane = threadIdx.x & 63;
    const float* xr = x + (size_t)row * 640;
    float v[10];
    float s = 0.f, s2 = 0.f;
#pragma unroll
    for (int i = 0; i < 10; ++i) {
        v[i] = xr[lane + i * 64];
        s += v[i]; s2 += v[i] * v[i];
    }
    for (int m = 1; m < 64; m <<= 1) { s += __shfl_xor(s, m); s2 += __shfl_xor(s2, m); }
    float mu = s * (1.f / 640.f);
    float var = s2 * (1.f / 640.f) - mu * mu;
    float r = rsqrtf(var + 1e-5f);
    float* orow = o + (size_t)row * 640;
#pragma unroll
    for (int i = 0; i < 10; ++i) {
        int c = lane + i * 64;
        orow[c] = (v[i] - mu) * r * g[c] + b[c];
    }
}

// ------------------------------ GEMM (fp32) ---------------------------------
// C[M,N] = A[M,K] @ B (+bias, epilogue). TRANSB: B stored [N,K] (ldb=K).
// 128x128 tile, BK=16, 8x8 per-thread micro-tile.
enum { EPI_STORE = 0, EPI_RES = 1, EPI_GEGLU = 2, EPI_CONVT = 3 };

template <int EPI, bool TRANSB>
__global__ __launch_bounds__(256) void gemm_k(const float* __restrict__ A, int lda,
                                              const float* __restrict__ B, int ldb,
                                              const float* __restrict__ bias,
                                              float* __restrict__ C, int ldc,
                                              const float* __restrict__ aux,
                                              int M, int N, int K) {
    __shared__ float As[16][132];
    __shared__ float Bs[16][132];
    const int t = threadIdx.x;
    const int m0 = blockIdx.x * 128;
    const int n0 = blockIdx.y * 128;
    const int tm = t >> 4;   // 0..15
    const int tn = t & 15;   // 0..15

    float acc[8][8];
#pragma unroll
    for (int i = 0; i < 8; ++i)
#pragma unroll
        for (int j = 0; j < 8; ++j) acc[i][j] = 0.f;

    for (int k0 = 0; k0 < K; k0 += 16) {
        float4 av[2], bv[2];
#pragma unroll
        for (int i = 0; i < 2; ++i) {
            int lin = t + i * 256;       // 0..511
            int row = lin >> 2;          // 0..127
            int kq = (lin & 3) * 4;
            float4 v = make_float4(0.f, 0.f, 0.f, 0.f);
            if (m0 + row < M)
                v = *(const float4*)(A + (size_t)(m0 + row) * lda + k0 + kq);
            av[i] = v;
            if (TRANSB) {
                bv[i] = *(const float4*)(B + (size_t)(n0 + row) * ldb + k0 + kq);
            } else {
                int krow = lin >> 5;     // 0..15
                int nq = (lin & 31) * 4;
                bv[i] = *(const float4*)(B + (size_t)(k0 + krow) * ldb + n0 + nq);
            }
        }
        __syncthreads();
#pragma unroll
        for (int i = 0; i < 2; ++i) {
            int lin = t + i * 256;
            int row = lin >> 2;
            int kq = (lin & 3) * 4;
            As[kq + 0][row] = av[i].x; As[kq + 1][row] = av[i].y;
            As[kq + 2][row] = av[i].z; As[kq + 3][row] = av[i].w;
            if (TRANSB) {
                Bs[kq + 0][row] = bv[i].x; Bs[kq + 1][row] = bv[i].y;
                Bs[kq + 2][row] = bv[i].z; Bs[kq + 3][row] = bv[i].w;
            } else {
                int krow = lin >> 5;
                int nq = (lin & 31) * 4;
                *(float4*)&Bs[krow][nq] = bv[i];
            }
        }
        __syncthreads();
#pragma unroll
        for (int kk = 0; kk < 16; ++kk) {
            float a[8], b[8];
            *(float4*)&a[0] = *(const float4*)&As[kk][tm * 8];
            *(float4*)&a[4] = *(const float4*)&As[kk][tm * 8 + 4];
            *(float4*)&b[0] = *(const float4*)&Bs[kk][tn * 8];
            *(float4*)&b[4] = *(const float4*)&Bs[kk][tn * 8 + 4];
#pragma unroll
            for (int i = 0; i < 8; ++i)
#pragma unroll
                for (int j = 0; j < 8; ++j) acc[i][j] += a[i] * b[j];
        }
    }

    float bj[8];
#pragma unroll
    for (int j = 0; j < 8; ++j) bj[j] = bias ? bias[n0 + tn * 8 + j] : 0.f;

    if (EPI == EPI_CONVT) {
        // write transposed into [n][c][p] layout, + long residual from aux
        const int mbase = m0 + tm * 8;
        const int bch = mbase >> 10;
        const int p = mbase & 1023;
#pragma unroll
        for (int j = 0; j < 8; ++j) {
            size_t col = (size_t)bch * 655360 + (size_t)(n0 + tn * 8 + j) * 1024 + p;
            float4 r0 = *(const float4*)(aux + col);
            float4 r1 = *(const float4*)(aux + col + 4);
            float4 v0, v1;
            v0.x = acc[0][j] + bj[j] + r0.x; v0.y = acc[1][j] + bj[j] + r0.y;
            v0.z = acc[2][j] + bj[j] + r0.z; v0.w = acc[3][j] + bj[j] + r0.w;
            v1.x = acc[4][j] + bj[j] + r1.x; v1.y = acc[5][j] + bj[j] + r1.y;
            v1.z = acc[6][j] + bj[j] + r1.z; v1.w = acc[7][j] + bj[j] + r1.w;
            *(float4*)(C + col) = v0;
            *(float4*)(C + col + 4) = v1;
        }
    } else {
#pragma unroll
        for (int i = 0; i < 8; ++i) {
            int m = m0 + tm * 8 + i;
            if (m >= M) continue;
            float* cr = C + (size_t)m * ldc + n0 + tn * 8;
#pragma unroll
            for (int hh = 0; hh < 2; ++hh) {
                float4 v;
                v.x = acc[i][hh * 4 + 0] + bj[hh * 4 + 0];
                v.y = acc[i][hh * 4 + 1] + bj[hh * 4 + 1];
                v.z = acc[i][hh * 4 + 2] + bj[hh * 4 + 2];
                v.w = acc[i][hh * 4 + 3] + bj[hh * 4 + 3];
                if (EPI == EPI_RES) {
                    float4 c0 = *(const float4*)(cr + hh * 4);
                    v.x += c0.x; v.y += c0.y; v.z += c0.z; v.w += c0.w;
                } else if (EPI == EPI_GEGLU) {
                    float4 a0 = *(const float4*)(cr + hh * 4);
                    v.x = a0.x * gelu_f(v.x); v.y = a0.y * gelu_f(v.y);
                    v.z = a0.z * gelu_f(v.z); v.w = a0.w * gelu_f(v.w);
                }
                *(float4*)(cr + hh * 4) = v;
            }
        }
    }
}

// -------------------- flash attention (online softmax, fp32) ----------------
// Grid: (sq/32, heads, batch). BQ=32, BK=64, DH=80.
__global__ __launch_bounds__(256) void attn_k(const float* __restrict__ Qp, int qstride,
                                              const float* __restrict__ Kp, int kstride,
                                              const float* __restrict__ Vp, int vstride,
                                              float* __restrict__ Op, int ostride,
                                              int sq, int sk, float scale) {
    const int b = blockIdx.z, h = blockIdx.y;
    const int q0 = blockIdx.x * 32;
    const int t = threadIdx.x;

    __shared__ float Qs[32][84];
    __shared__ float Ks[64][84];
    __shared__ float Vs[64][84];
    __shared__ float Ss[32][68];
    __shared__ float alpha_s[32];
    __shared__ float l_s[32];

    // load + pre-scale Q tile
    for (int lin = t; lin < 640; lin += 256) {
        int row = lin / 20, c = lin % 20;
        float4 v = *(const float4*)(Qp + (size_t)(b * sq + q0 + row) * qstride + h * DH + c * 4);
        float4 w; w.x = v.x * scale; w.y = v.y * scale; w.z = v.z * scale; w.w = v.w * scale;
        *(float4*)&Qs[row][c * 4] = w;
    }

    const int qg = t >> 4;   // 0..15  (score phase: 2 q-rows each)
    const int kg = t & 15;   // 0..15  (score phase: k = kg + 16j)
    const int pq = t >> 3;   // 0..31  (PV phase: one q-row)
    const int dg = t & 7;    // 0..7   (PV phase: dims dg*4, 32+dg*4, [64+dg*4])

    float m0r = -1e30f, m1r = -1e30f;
    float l0 = 0.f, l1 = 0.f;
    float4 o0 = {0, 0, 0, 0}, o1 = {0, 0, 0, 0}, o2 = {0, 0, 0, 0};

    const int nkt = (sk + 63) >> 6;
    for (int kt = 0; kt < nkt; ++kt) {
        __syncthreads();  // protect Ks/Vs/Ss from prior iteration's readers (and Qs on first)
#pragma unroll
        for (int i = 0; i < 5; ++i) {
            int lin = t + i * 256;     // 0..1279
            int row = lin / 20, c = lin % 20;
            int kr = kt * 64 + row;
            float4 kvk = {0, 0, 0, 0}, kvv = {0, 0, 0, 0};
            if (kr < sk) {
                kvk = *(const float4*)(Kp + (size_t)(b * sk + kr) * kstride + h * DH + c * 4);
                kvv = *(const float4*)(Vp + (size_t)(b * sk + kr) * vstride + h * DH + c * 4);
            }
            *(float4*)&Ks[row][c * 4] = kvk;
            *(float4*)&Vs[row][c * 4] = kvv;
        }
        __syncthreads();

        // scores for q rows {qg*2, qg*2+1}, k = kg + 16j
        float s0[4] = {0, 0, 0, 0}, s1[4] = {0, 0, 0, 0};
#pragma unroll
        for (int d4 = 0; d4 < 20; ++d4) {
            float4 qa = *(const float4*)&Qs[qg * 2 + 0][d4 * 4];
            float4 qb = *(const float4*)&Qs[qg * 2 + 1][d4 * 4];
#pragma unroll
            for (int j = 0; j < 4; ++j) {
                float4 kk = *(const float4*)&Ks[kg + 16 * j][d4 * 4];
                s0[j] += qa.x * kk.x + qa.y * kk.y + qa.z * kk.z + qa.w * kk.w;
                s1[j] += qb.x * kk.x + qb.y * kk.y + qb.z * kk.z + qb.w * kk.w;
            }
        }
#pragma unroll
        for (int j = 0; j < 4; ++j)
            if (kt * 64 + kg + 16 * j >= sk) { s0[j] = -1e30f; s1[j] = -1e30f; }

        float mx0 = fmaxf(fmaxf(s0[0], s0[1]), fmaxf(s0[2], s0[3]));
        float mx1 = fmaxf(fmaxf(s1[0], s1[1]), fmaxf(s1[2], s1[3]));
        for (int m = 1; m < 16; m <<= 1) {
            mx0 = fmaxf(mx0, __shfl_xor(mx0, m));
            mx1 = fmaxf(mx1, __shfl_xor(mx1, m));
        }
        float mn0 = fmaxf(m0r, mx0), mn1 = fmaxf(m1r, mx1);
        float al0 = __expf(m0r - mn0), al1 = __expf(m1r - mn1);
        float su0 = 0.f, su1 = 0.f;
        float p0[4], p1[4];
#pragma unroll
        for (int j = 0; j < 4; ++j) {
            p0[j] = __expf(s0[j] - mn0); su0 += p0[j];
            p1[j] = __expf(s1[j] - mn1); su1 += p1[j];
        }
        for (int m = 1; m < 16; m <<= 1) {
            su0 += __shfl_xor(su0, m);
            su1 += __shfl_xor(su1, m);
        }
        l0 = l0 * al0 + su0; l1 = l1 * al1 + su1;
        m0r = mn0; m1r = mn1;
#pragma unroll
        for (int j = 0; j < 4; ++j) {
            Ss[qg * 2 + 0][kg + 16 * j] = p0[j];
            Ss[qg * 2 + 1][kg + 16 * j] = p1[j];
        }
        if (kg == 0) { alpha_s[qg * 2] = al0; alpha_s[qg * 2 + 1] = al1; }
        __syncthreads();

        // PV: o[pq][dims] accumulate
        float al = alpha_s[pq];
        o0.x *= al; o0.y *= al; o0.z *= al; o0.w *= al;
        o1.x *= al; o1.y *= al; o1.z *= al; o1.w *= al;
        o2.x *= al; o2.y *= al; o2.z *= al; o2.w *= al;
#pragma unroll 4
        for (int k = 0; k < 64; ++k) {
            float p = Ss[pq][k];
            float4 va = *(const float4*)&Vs[k][dg * 4];
            float4 vb = *(const float4*)&Vs[k][32 + dg * 4];
            o0.x += p * va.x; o0.y += p * va.y; o0.z += p * va.z; o0.w += p * va.w;
            o1.x += p * vb.x; o1.y += p * vb.y; o1.z += p * vb.z; o1.w += p * vb.w;
            if (dg < 4) {
                float4 vc = *(const float4*)&Vs[k][64 + dg * 4];
                o2.x += p * vc.x; o2.y += p * vc.y; o2.z += p * vc.z; o2.w += p * vc.w;
            }
        }
    }

    if (kg == 0) { l_s[qg * 2] = l0; l_s[qg * 2 + 1] = l1; }
    __syncthreads();
    float inv = 1.f / l_s[pq];
    float* orow = Op + (size_t)(b * sq + q0 + pq) * ostride + h * DH;
    float4 w0, w1;
    w0.x = o0.x * inv; w0.y = o0.y * inv; w0.z = o0.z * inv; w0.w = o0.w * inv;
    w1.x = o1.x * inv; w1.y = o1.y * inv; w1.z = o1.z * inv; w1.w = o1.w * inv;
    *(float4*)(orow + dg * 4) = w0;
    *(float4*)(orow + 32 + dg * 4) = w1;
    if (dg < 4) {
        float4 w2;
        w2.x = o2.x * inv; w2.y = o2.y * inv; w2.z = o2.z * inv; w2.w = o2.w * inv;
        *(float4*)(orow + 64 + dg * 4) = w2;
    }
}

// ---------------------------------------------------------------------------
extern "C" void kernel_launch(void* const* d_in, const int* in_sizes, int n_in,
                              void* d_out, int out_size, void* d_ws, size_t ws_size,
                              hipStream_t stream) {
    const float* x        = (const float*)d_in[0];
    const float* ctx      = (const float*)d_in[1];
    const float* gn_s     = (const float*)d_in[2];
    const float* gn_b     = (const float*)d_in[3];
    const float* conv1_w  = (const float*)d_in[4];
    const float* conv1_b  = (const float*)d_in[5];
    const float* ln1_s    = (const float*)d_in[6];
    const float* ln1_b    = (const float*)d_in[7];
    const float* sa_in_w  = (const float*)d_in[8];
    const float* sa_out_w = (const float*)d_in[9];
    const float* sa_out_b = (const float*)d_in[10];
    const float* ln2_s    = (const float*)d_in[11];
    const float* ln2_b    = (const float*)d_in[12];
    const float* ca_q_w   = (const float*)d_in[13];
    const float* ca_k_w   = (const float*)d_in[14];
    const float* ca_v_w   = (const float*)d_in[15];
    const float* ca_out_w = (const float*)d_in[16];
    const float* ca_out_b = (const float*)d_in[17];
    const float* ln3_s    = (const float*)d_in[18];
    const float* ln3_b    = (const float*)d_in[19];
    const float* lin1_w   = (const float*)d_in[20];
    const float* lin1_b   = (const float*)d_in[21];
    const float* lin2_w   = (const float*)d_in[22];
    const float* lin2_b   = (const float*)d_in[23];
    const float* co_w     = (const float*)d_in[24];
    const float* co_b     = (const float*)d_in[25];

    float* out = (float*)d_out;
    float* ws = (float*)d_ws;

    // ws layout (floats): x_seq | ctx K/V | u (qkv / FFN union) | gn stats
    float* x_seq = ws;                   // 8192*640   = 5,242,880
    float* kv    = ws + 5242880;         // 2*616*640  =   788,480
    float* u     = ws + 6031360;         // 8192*2560  = 20,971,520
    float* stats = ws + 27002880;        // 512
    float* tbuf  = out;                  // 8192*640 — reuse d_out as the 't' buffer

    const float scale = 0.11180339887498949f;  // 1/sqrt(80)

    // 1. GroupNorm + transpose to token-major
    gn_stats_k<<<256, 256, 0, stream>>>(x, stats);
    gn_apply_t_k<<<dim3(32, 20, 8), 256, 0, stream>>>(x, stats, gn_s, gn_b, tbuf);
    // 2. conv1 (W is [out,in] -> TRANSB)
    gemm_k<EPI_STORE, true><<<dim3(64, 5), 256, 0, stream>>>(tbuf, 640, conv1_w, 640, conv1_b, x_seq, 640, nullptr, 8192, 640, 640);
    // 3. LN1 + QKV + self-attention + out-proj (+residual)
    ln_k<<<2048, 256, 0, stream>>>(x_seq, ln1_s, ln1_b, tbuf);
    gemm_k<EPI_STORE, false><<<dim3(64, 15), 256, 0, stream>>>(tbuf, 640, sa_in_w, 1920, nullptr, u, 1920, nullptr, 8192, 1920, 640);
    attn_k<<<dim3(32, 8, 8), 256, 0, stream>>>(u, 1920, u + 640, 1920, u + 1280, 1920, tbuf, 640, 1024, 1024, scale);
    gemm_k<EPI_RES, false><<<dim3(64, 5), 256, 0, stream>>>(tbuf, 640, sa_out_w, 640, sa_out_b, x_seq, 640, nullptr, 8192, 640, 640);
    // 4. LN2 + cross-attention (+residual)
    ln_k<<<2048, 256, 0, stream>>>(x_seq, ln2_s, ln2_b, tbuf);
    gemm_k<EPI_STORE, false><<<dim3(64, 5), 256, 0, stream>>>(tbuf, 640, ca_q_w, 640, nullptr, u, 640, nullptr, 8192, 640, 640);
    gemm_k<EPI_STORE, false><<<dim3(5, 5), 256, 0, stream>>>(ctx, 512, ca_k_w, 640, nullptr, kv, 640, nullptr, 616, 640, 512);
    gemm_k<EPI_STORE, false><<<dim3(5, 5), 256, 0, stream>>>(ctx, 512, ca_v_w, 640, nullptr, kv + 394240, 640, nullptr, 616, 640, 512);
    attn_k<<<dim3(32, 8, 8), 256, 0, stream>>>(u, 640, kv, 640, kv + 394240, 640, tbuf, 640, 1024, 77, scale);
    gemm_k<EPI_RES, false><<<dim3(64, 5), 256, 0, stream>>>(tbuf, 640, ca_out_w, 640, ca_out_b, x_seq, 640, nullptr, 8192, 640, 640);
    // 5. LN3 + GeGLU FFN (+residual)
    ln_k<<<2048, 256, 0, stream>>>(x_seq, ln3_s, ln3_b, tbuf);
    gemm_k<EPI_STORE, false><<<dim3(64, 20), 256, 0, stream>>>(tbuf, 640, lin1_w, 5120, lin1_b, u, 2560, nullptr, 8192, 2560, 640);
    gemm_k<EPI_GEGLU, false><<<dim3(64, 20), 256, 0, stream>>>(tbuf, 640, lin1_w + 2560, 5120, lin1_b + 2560, u, 2560, nullptr, 8192, 2560, 640);
    gemm_k<EPI_RES, false><<<dim3(64, 5), 256, 0, stream>>>(u, 2560, lin2_w, 640, lin2_b, x_seq, 640, nullptr, 8192, 640, 2560);
    // 6. final conv1x1 (TRANSB) + transpose-write + long residual
    gemm_k<EPI_CONVT, true><<<dim3(64, 5), 256, 0, stream>>>(x_seq, 640, co_w, 640, co_b, out, 0, x, 8192, 640, 640);
}

// Round 2
// 2073.411 us; speedup vs baseline: 1.8421x; 1.8421x over previous
//
#include <hip/hip_runtime.h>

// ---------------------------------------------------------------------------
// AttentionBlock (SD-style). Round 2: all GEMMs -> bf16 MFMA (m97 structure:
// 128x128 tile, BK=32, global_load_lds width-16, mfma_f32_16x16x32_bf16).
// Attention stays fp32-compute but with bf16 I/O. Residual stream fp32.
// B=8, C=640, HW=1024, H=8, DH=80, CTX 77x512.
// ---------------------------------------------------------------------------

#define DH 80

typedef __attribute__((ext_vector_type(8))) short bf16x8;
typedef __attribute__((ext_vector_type(4))) float floatx4;

static __device__ __forceinline__ float gelu_f(float x) {
    return 0.5f * x * (1.0f + erff(x * 0.70710678118654752f));
}
static __device__ __forceinline__ unsigned short f2bf(float f) {
    unsigned u = __float_as_uint(f);
    u = (u + 0x7fffu + ((u >> 16) & 1u)) >> 16;
    return (unsigned short)u;
}
static __device__ __forceinline__ float bf2f(unsigned short s) {
    return __uint_as_float(((unsigned)s) << 16);
}
static __device__ __forceinline__ float4 ld4bf(const unsigned short* p) {
    ushort4 u = *(const ushort4*)p;
    float4 f;
    f.x = bf2f(u.x); f.y = bf2f(u.y); f.z = bf2f(u.z); f.w = bf2f(u.w);
    return f;
}
static __device__ __forceinline__ void st4bf(unsigned short* p, float4 v) {
    ushort4 u;
    u.x = f2bf(v.x); u.y = f2bf(v.y); u.z = f2bf(v.z); u.w = f2bf(v.w);
    *(ushort4*)p = u;
}
static __device__ __forceinline__ void async_copy16(const void* g, void* l) {
    __builtin_amdgcn_global_load_lds(
        (const __attribute__((address_space(1))) unsigned int*)g,
        (__attribute__((address_space(3))) unsigned int*)l, 16, 0, 0);
}

// ------------------------- GroupNorm stats ---------------------------------
__global__ __launch_bounds__(256) void gn_stats_k(const float* __restrict__ x,
                                                  float* __restrict__ stats) {
    const int ng = blockIdx.x;                       // n*32 + g
    const float4* base = (const float4*)(x + (size_t)ng * 20480);
    float s = 0.f, s2 = 0.f;
    for (int i = threadIdx.x; i < 5120; i += 256) {
        float4 v = base[i];
        s  += v.x + v.y + v.z + v.w;
        s2 += v.x*v.x + v.y*v.y + v.z*v.z + v.w*v.w;
    }
    for (int m = 1; m < 64; m <<= 1) { s += __shfl_xor(s, m); s2 += __shfl_xor(s2, m); }
    __shared__ float rs[4], rs2[4];
    if ((threadIdx.x & 63) == 0) { rs[threadIdx.x >> 6] = s; rs2[threadIdx.x >> 6] = s2; }
    __syncthreads();
    if (threadIdx.x == 0) {
        float ts = rs[0] + rs[1] + rs[2] + rs[3];
        float t2 = rs2[0] + rs2[1] + rs2[2] + rs2[3];
        float mu = ts * (1.f / 20480.f);
        float var = t2 * (1.f / 20480.f) - mu * mu;
        stats[ng * 2]     = mu;
        stats[ng * 2 + 1] = rsqrtf(var + 1e-6f);
    }
}

// ----------------- GroupNorm apply + transpose, bf16 out --------------------
__global__ __launch_bounds__(256) void gn_apply_t_k(const float* __restrict__ x,
                                                    const float* __restrict__ stats,
                                                    const float* __restrict__ gs,
                                                    const float* __restrict__ gb,
                                                    unsigned short* __restrict__ out) {
    const int p0 = blockIdx.x * 32, c0 = blockIdx.y * 32, n = blockIdx.z;
    __shared__ float tile[32][33];
    const int t = threadIdx.x;
    {
        const int cl = t >> 5, pl = t & 31;
#pragma unroll
        for (int i = 0; i < 4; ++i) {
            int c = c0 + cl + i * 8;
            int g = c / 20;
            float mu = stats[(n * 32 + g) * 2];
            float rstd = stats[(n * 32 + g) * 2 + 1];
            float v = x[(size_t)n * 655360 + (size_t)c * 1024 + p0 + pl];
            tile[cl + i * 8][pl] = (v - mu) * rstd * gs[c] + gb[c];
        }
    }
    __syncthreads();
    {
        const int pl = t >> 5, cl = t & 31;
#pragma unroll
        for (int i = 0; i < 4; ++i) {
            int p = p0 + pl + i * 8;
            out[((size_t)n * 1024 + p) * 640 + c0 + cl] = f2bf(tile[cl][pl + i * 8]);
        }
    }
}

// --------------------------- LayerNorm, bf16 out ----------------------------
__global__ __launch_bounds__(256) void ln_k(const float* __restrict__ x,
                                            const float* __restrict__ g,
                                            const float* __restrict__ b,
                                            unsigned short* __restrict__ o) {
    const int row = blockIdx.x * 4 + (threadIdx.x >> 6);
    const int lane = threadIdx.x & 63;
    const float* xr = x + (size_t)row * 640;
    float v[10];
    float s = 0.f, s2 = 0.f;
#pragma unroll
    for (int i = 0; i < 10; ++i) {
        v[i] = xr[lane + i * 64];
        s += v[i]; s2 += v[i] * v[i];
    }
    for (int m = 1; m < 64; m <<= 1) { s += __shfl_xor(s, m); s2 += __shfl_xor(s2, m); }
    float mu = s * (1.f / 640.f);
    float var = s2 * (1.f / 640.f) - mu * mu;
    float r = rsqrtf(var + 1e-5f);
    unsigned short* orow = o + (size_t)row * 640;
#pragma unroll
    for (int i = 0; i < 10; ++i) {
        int c = lane + i * 64;
        orow[c] = f2bf((v[i] - mu) * r * g[c] + b[c]);
    }
}

// -------------------- weight prep: fp32 -> bf16 -----------------------------
__global__ __launch_bounds__(256) void wcvt_k(const float* __restrict__ W,
                                              unsigned short* __restrict__ O, int n) {
    int i = blockIdx.x * 256 + threadIdx.x;
    if (i < n) O[i] = f2bf(W[i]);
}
// [K][N] fp32 -> [N][K] bf16
__global__ __launch_bounds__(256) void wtr_k(const float* __restrict__ W, int K, int N,
                                             unsigned short* __restrict__ O) {
    __shared__ float tile[32][33];
    const int k0 = blockIdx.x * 32, n0 = blockIdx.y * 32;
    const int tr = threadIdx.x >> 5, tc = threadIdx.x & 31;
#pragma unroll
    for (int i = 0; i < 4; ++i)
        tile[tr + i * 8][tc] = W[(size_t)(k0 + tr + i * 8) * N + n0 + tc];
    __syncthreads();
#pragma unroll
    for (int i = 0; i < 4; ++i)
        O[(size_t)(n0 + tr + i * 8) * K + k0 + tc] = f2bf(tile[tc][tr + i * 8]);
}
// ctx [616][512] fp32 -> [640][512] bf16 zero-padded
__global__ __launch_bounds__(256) void ctxcvt_k(const float* __restrict__ ctx,
                                                unsigned short* __restrict__ O) {
    int i = blockIdx.x * 256 + threadIdx.x;
    if (i < 640 * 512) {
        int r = i >> 9;
        O[i] = (r < 616) ? f2bf(ctx[i]) : (unsigned short)0;
    }
}

// --------------------------- bf16 MFMA GEMM ---------------------------------
// C[M,N] = A[M,K] * B^T[N,K] (+bias, epilogue). M%128==0, N%128==0, K%32==0.
// A,B bf16 row-major. 128x128 tile, BK=32, 4 waves, 4x4 16x16 frags per wave.
enum { EPI_OUT = 0, EPI_RES = 1, EPI_GEGLU = 2, EPI_CONVT = 3 };

template <int EPI, typename CT>
__global__ __launch_bounds__(256) void bgemm_k(const unsigned short* __restrict__ A, int lda,
                                               const unsigned short* __restrict__ B, int ldb,
                                               const float* __restrict__ bias,
                                               CT* __restrict__ C, int ldc,
                                               const float* __restrict__ aux,
                                               int M, int N, int K) {
    __shared__ __attribute__((aligned(16))) short As[128 * 32];
    __shared__ __attribute__((aligned(16))) short Bs[128 * 32];
    const int t = threadIdx.x;
    const int lane = t & 63;
    const int w = __builtin_amdgcn_readfirstlane(t >> 6);
    const int m0 = blockIdx.x * 128, n0 = blockIdx.y * 128;
    const int wm = (w >> 1) * 64, wn = (w & 1) * 64;

    const int sr = lane >> 2;          // staging row within 16-row group
    const int sc = (lane & 3) * 8;     // staging col (elements)
    const int fm = lane & 15;          // fragment row/col
    const int fq = (lane >> 4) * 8;    // fragment k offset

    floatx4 acc[4][4];
#pragma unroll
    for (int i = 0; i < 4; ++i)
#pragma unroll
        for (int j = 0; j < 4; ++j) acc[i][j] = (floatx4){0.f, 0.f, 0.f, 0.f};

    for (int k0 = 0; k0 < K; k0 += 32) {
        const unsigned short* a0 = A + (size_t)(m0 + w * 16 + sr) * lda + k0 + sc;
        const unsigned short* b0 = B + (size_t)(n0 + w * 16 + sr) * ldb + k0 + sc;
        async_copy16(a0,                 As + (w * 16) * 32);
        async_copy16(a0 + (size_t)64 * lda, As + (64 + w * 16) * 32);
        async_copy16(b0,                 Bs + (w * 16) * 32);
        async_copy16(b0 + (size_t)64 * ldb, Bs + (64 + w * 16) * 32);
        __syncthreads();
        bf16x8 af[4], bfr[4];
#pragma unroll
        for (int i = 0; i < 4; ++i) {
            af[i]  = *(const bf16x8*)(As + (wm + i * 16 + fm) * 32 + fq);
            bfr[i] = *(const bf16x8*)(Bs + (wn + i * 16 + fm) * 32 + fq);
        }
#pragma unroll
        for (int i = 0; i < 4; ++i)
#pragma unroll
            for (int j = 0; j < 4; ++j)
                acc[i][j] = __builtin_amdgcn_mfma_f32_16x16x32_bf16(af[i], bfr[j], acc[i][j], 0, 0, 0);
        __syncthreads();
    }

    float bv[4];
#pragma unroll
    for (int j = 0; j < 4; ++j) bv[j] = bias ? bias[n0 + wn + j * 16 + fm] : 0.f;
    const int rbase = (lane >> 4) * 4;

#pragma unroll
    for (int i = 0; i < 4; ++i) {
#pragma unroll
        for (int j = 0; j < 4; ++j) {
            const int n = n0 + wn + j * 16 + fm;
#pragma unroll
            for (int r = 0; r < 4; ++r) {
                const int m = m0 + wm + i * 16 + rbase + r;
                float v = acc[i][j][r] + bv[j];
                if constexpr (EPI == EPI_OUT) {
                    if constexpr (__is_same(CT, float)) {
                        C[(size_t)m * ldc + n] = v;
                    } else {
                        C[(size_t)m * ldc + n] = f2bf(v);
                    }
                } else if constexpr (EPI == EPI_RES) {
                    C[(size_t)m * ldc + n] += v;
                } else if constexpr (EPI == EPI_GEGLU) {
                    float a = aux[(size_t)m * ldc + n];
                    C[(size_t)m * ldc + n] = f2bf(a * gelu_f(v));
                } else {  // EPI_CONVT: transposed write + long residual
                    const int bch = m >> 10, p = m & 1023;
                    const size_t idx = (size_t)bch * 655360 + (size_t)n * 1024 + p;
                    C[idx] = v + aux[idx];
                }
            }
        }
    }
}

// -------------------- flash attention (fp32 compute, bf16 I/O) --------------
__global__ __launch_bounds__(256) void attn_k(const unsigned short* __restrict__ Qp, int qstride,
                                              const unsigned short* __restrict__ Kp, int kstride,
                                              const unsigned short* __restrict__ Vp, int vstride,
                                              unsigned short* __restrict__ Op, int ostride,
                                              int sq, int sk, float scale) {
    const int b = blockIdx.z, h = blockIdx.y;
    const int q0 = blockIdx.x * 32;
    const int t = threadIdx.x;

    __shared__ float Qs[32][84];
    __shared__ float Ks[64][84];
    __shared__ float Vs[64][84];
    __shared__ float Ss[32][68];
    __shared__ float alpha_s[32];
    __shared__ float l_s[32];

    for (int lin = t; lin < 640; lin += 256) {
        int row = lin / 20, c = lin % 20;
        float4 v = ld4bf(Qp + (size_t)(b * sq + q0 + row) * qstride + h * DH + c * 4);
        float4 w2; w2.x = v.x * scale; w2.y = v.y * scale; w2.z = v.z * scale; w2.w = v.w * scale;
        *(float4*)&Qs[row][c * 4] = w2;
    }

    const int qg = t >> 4;
    const int kg = t & 15;
    const int pq = t >> 3;
    const int dg = t & 7;

    float m0r = -1e30f, m1r = -1e30f;
    float l0 = 0.f, l1 = 0.f;
    float4 o0 = {0, 0, 0, 0}, o1 = {0, 0, 0, 0}, o2 = {0, 0, 0, 0};

    const int nkt = (sk + 63) >> 6;
    for (int kt = 0; kt < nkt; ++kt) {
        __syncthreads();
#pragma unroll
        for (int i = 0; i < 5; ++i) {
            int lin = t + i * 256;
            int row = lin / 20, c = lin % 20;
            int kr = kt * 64 + row;
            float4 kvk = {0, 0, 0, 0}, kvv = {0, 0, 0, 0};
            if (kr < sk) {
                kvk = ld4bf(Kp + (size_t)(b * sk + kr) * kstride + h * DH + c * 4);
                kvv = ld4bf(Vp + (size_t)(b * sk + kr) * vstride + h * DH + c * 4);
            }
            *(float4*)&Ks[row][c * 4] = kvk;
            *(float4*)&Vs[row][c * 4] = kvv;
        }
        __syncthreads();

        float s0[4] = {0, 0, 0, 0}, s1[4] = {0, 0, 0, 0};
#pragma unroll
        for (int d4 = 0; d4 < 20; ++d4) {
            float4 qa = *(const float4*)&Qs[qg * 2 + 0][d4 * 4];
            float4 qb = *(const float4*)&Qs[qg * 2 + 1][d4 * 4];
#pragma unroll
            for (int j = 0; j < 4; ++j) {
                float4 kk = *(const float4*)&Ks[kg + 16 * j][d4 * 4];
                s0[j] += qa.x * kk.x + qa.y * kk.y + qa.z * kk.z + qa.w * kk.w;
                s1[j] += qb.x * kk.x + qb.y * kk.y + qb.z * kk.z + qb.w * kk.w;
            }
        }
#pragma unroll
        for (int j = 0; j < 4; ++j)
            if (kt * 64 + kg + 16 * j >= sk) { s0[j] = -1e30f; s1[j] = -1e30f; }

        float mx0 = fmaxf(fmaxf(s0[0], s0[1]), fmaxf(s0[2], s0[3]));
        float mx1 = fmaxf(fmaxf(s1[0], s1[1]), fmaxf(s1[2], s1[3]));
        for (int m = 1; m < 16; m <<= 1) {
            mx0 = fmaxf(mx0, __shfl_xor(mx0, m));
            mx1 = fmaxf(mx1, __shfl_xor(mx1, m));
        }
        float mn0 = fmaxf(m0r, mx0), mn1 = fmaxf(m1r, mx1);
        float al0 = __expf(m0r - mn0), al1 = __expf(m1r - mn1);
        float su0 = 0.f, su1 = 0.f;
        float p0[4], p1[4];
#pragma unroll
        for (int j = 0; j < 4; ++j) {
            p0[j] = __expf(s0[j] - mn0); su0 += p0[j];
            p1[j] = __expf(s1[j] - mn1); su1 += p1[j];
        }
        for (int m = 1; m < 16; m <<= 1) {
            su0 += __shfl_xor(su0, m);
            su1 += __shfl_xor(su1, m);
        }
        l0 = l0 * al0 + su0; l1 = l1 * al1 + su1;
        m0r = mn0; m1r = mn1;
#pragma unroll
        for (int j = 0; j < 4; ++j) {
            Ss[qg * 2 + 0][kg + 16 * j] = p0[j];
            Ss[qg * 2 + 1][kg + 16 * j] = p1[j];
        }
        if (kg == 0) { alpha_s[qg * 2] = al0; alpha_s[qg * 2 + 1] = al1; }
        __syncthreads();

        float al = alpha_s[pq];
        o0.x *= al; o0.y *= al; o0.z *= al; o0.w *= al;
        o1.x *= al; o1.y *= al; o1.z *= al; o1.w *= al;
        o2.x *= al; o2.y *= al; o2.z *= al; o2.w *= al;
#pragma unroll 4
        for (int k = 0; k < 64; ++k) {
            float p = Ss[pq][k];
            float4 va = *(const float4*)&Vs[k][dg * 4];
            float4 vb = *(const float4*)&Vs[k][32 + dg * 4];
            o0.x += p * va.x; o0.y += p * va.y; o0.z += p * va.z; o0.w += p * va.w;
            o1.x += p * vb.x; o1.y += p * vb.y; o1.z += p * vb.z; o1.w += p * vb.w;
            if (dg < 4) {
                float4 vc = *(const float4*)&Vs[k][64 + dg * 4];
                o2.x += p * vc.x; o2.y += p * vc.y; o2.z += p * vc.z; o2.w += p * vc.w;
            }
        }
    }

    if (kg == 0) { l_s[qg * 2] = l0; l_s[qg * 2 + 1] = l1; }
    __syncthreads();
    float inv = 1.f / l_s[pq];
    unsigned short* orow = Op + (size_t)(b * sq + q0 + pq) * ostride + h * DH;
    float4 w0, w1;
    w0.x = o0.x * inv; w0.y = o0.y * inv; w0.z = o0.z * inv; w0.w = o0.w * inv;
    w1.x = o1.x * inv; w1.y = o1.y * inv; w1.z = o1.z * inv; w1.w = o1.w * inv;
    st4bf(orow + dg * 4, w0);
    st4bf(orow + 32 + dg * 4, w1);
    if (dg < 4) {
        float4 w2;
        w2.x = o2.x * inv; w2.y = o2.y * inv; w2.z = o2.z * inv; w2.w = o2.w * inv;
        st4bf(orow + 64 + dg * 4, w2);
    }
}

// fp32 -> bf16 elementwise (activation copies)
__global__ __launch_bounds__(256) void acvt_k(const float* __restrict__ X,
                                              unsigned short* __restrict__ O, int n) {
    int i = blockIdx.x * 256 + threadIdx.x;
    if (i < n) O[i] = f2bf(X[i]);
}

// ---------------------------------------------------------------------------
extern "C" void kernel_launch(void* const* d_in, const int* in_sizes, int n_in,
                              void* d_out, int out_size, void* d_ws, size_t ws_size,
                              hipStream_t stream) {
    const float* x        = (const float*)d_in[0];
    const float* ctx      = (const float*)d_in[1];
    const float* gn_s     = (const float*)d_in[2];
    const float* gn_b     = (const float*)d_in[3];
    const float* conv1_w  = (const float*)d_in[4];
    const float* conv1_b  = (const float*)d_in[5];
    const float* ln1_s    = (const float*)d_in[6];
    const float* ln1_b    = (const float*)d_in[7];
    const float* sa_in_w  = (const float*)d_in[8];
    const float* sa_out_w = (const float*)d_in[9];
    const float* sa_out_b = (const float*)d_in[10];
    const float* ln2_s    = (const float*)d_in[11];
    const float* ln2_b    = (const float*)d_in[12];
    const float* ca_q_w   = (const float*)d_in[13];
    const float* ca_k_w   = (const float*)d_in[14];
    const float* ca_v_w   = (const float*)d_in[15];
    const float* ca_out_w = (const float*)d_in[16];
    const float* ca_out_b = (const float*)d_in[17];
    const float* ln3_s    = (const float*)d_in[18];
    const float* ln3_b    = (const float*)d_in[19];
    const float* lin1_w   = (const float*)d_in[20];
    const float* lin1_b   = (const float*)d_in[21];
    const float* lin2_w   = (const float*)d_in[22];
    const float* lin2_b   = (const float*)d_in[23];
    const float* co_w     = (const float*)d_in[24];
    const float* co_b     = (const float*)d_in[25];

    float* out = (float*)d_out;       // doubles as x_seq (fp32 residual stream)
    float* ws = (float*)d_ws;
    float* x_seq = out;

    // ws layout (float units)
    float* u_f      = ws;                              // [4096][2560] fp32 FFN a-half; also qkv/q/xf bf16 region
    unsigned short* u_b   = (unsigned short*)ws;       // qkv bf16 [8192][1920] / q_b [8192][640] / xf_b [8192][640]
    unsigned short* h_b   = (unsigned short*)(ws + 10485760);  // h half [4096][2560] bf16
    unsigned short* abuf  = (unsigned short*)(ws + 15728640);  // [8192][640] bf16
    unsigned short* kv0   = (unsigned short*)(ws + 18350080);  // [640][640] bf16
    unsigned short* kv1   = (unsigned short*)(ws + 18554880);
    unsigned short* ctx_b = (unsigned short*)(ws + 18759680);  // [640][512] bf16
    size_t woff = 18923520;
    unsigned short* conv1_wb  = (unsigned short*)(ws + woff); woff += 204800;
    unsigned short* sa_in_wb  = (unsigned short*)(ws + woff); woff += 614400;
    unsigned short* sa_out_wb = (unsigned short*)(ws + woff); woff += 204800;
    unsigned short* ca_q_wb   = (unsigned short*)(ws + woff); woff += 204800;
    unsigned short* ca_k_wb   = (unsigned short*)(ws + woff); woff += 163840;
    unsigned short* ca_v_wb   = (unsigned short*)(ws + woff); woff += 163840;
    unsigned short* ca_out_wb = (unsigned short*)(ws + woff); woff += 204800;
    unsigned short* lin1_wb   = (unsigned short*)(ws + woff); woff += 1638400;
    unsigned short* lin2_wb   = (unsigned short*)(ws + woff); woff += 819200;
    unsigned short* co_wb     = (unsigned short*)(ws + woff); woff += 204800;
    float* stats = ws + woff;

    const float scale = 0.11180339887498949f;  // 1/sqrt(80)

    // ---- weight prep (same work every call; graph-safe) ----
    wcvt_k<<<1600, 256, 0, stream>>>(conv1_w, conv1_wb, 409600);
    wcvt_k<<<1600, 256, 0, stream>>>(co_w, co_wb, 409600);
    ctxcvt_k<<<1280, 256, 0, stream>>>(ctx, ctx_b);
    wtr_k<<<dim3(20, 60), 256, 0, stream>>>(sa_in_w, 640, 1920, sa_in_wb);
    wtr_k<<<dim3(20, 20), 256, 0, stream>>>(sa_out_w, 640, 640, sa_out_wb);
    wtr_k<<<dim3(20, 20), 256, 0, stream>>>(ca_q_w, 640, 640, ca_q_wb);
    wtr_k<<<dim3(16, 20), 256, 0, stream>>>(ca_k_w, 512, 640, ca_k_wb);
    wtr_k<<<dim3(16, 20), 256, 0, stream>>>(ca_v_w, 512, 640, ca_v_wb);
    wtr_k<<<dim3(20, 20), 256, 0, stream>>>(ca_out_w, 640, 640, ca_out_wb);
    wtr_k<<<dim3(20, 160), 256, 0, stream>>>(lin1_w, 640, 5120, lin1_wb);
    wtr_k<<<dim3(80, 20), 256, 0, stream>>>(lin2_w, 2560, 640, lin2_wb);

    // ---- 1. GroupNorm + transpose (bf16) ----
    gn_stats_k<<<256, 256, 0, stream>>>(x, stats);
    gn_apply_t_k<<<dim3(32, 20, 8), 256, 0, stream>>>(x, stats, gn_s, gn_b, abuf);
    // ---- 2. conv1 -> x_seq fp32 ----
    bgemm_k<EPI_OUT, float><<<dim3(64, 5), 256, 0, stream>>>(abuf, 640, conv1_wb, 640, conv1_b, x_seq, 640, nullptr, 8192, 640, 640);
    // ---- 3. LN1 + QKV + self-attn + out-proj (+res) ----
    ln_k<<<2048, 256, 0, stream>>>(x_seq, ln1_s, ln1_b, abuf);
    bgemm_k<EPI_OUT, unsigned short><<<dim3(64, 15), 256, 0, stream>>>(abuf, 640, sa_in_wb, 640, nullptr, u_b, 1920, nullptr, 8192, 1920, 640);
    attn_k<<<dim3(32, 8, 8), 256, 0, stream>>>(u_b, 1920, u_b + 640, 1920, u_b + 1280, 1920, abuf, 640, 1024, 1024, scale);
    bgemm_k<EPI_RES, float><<<dim3(64, 5), 256, 0, stream>>>(abuf, 640, sa_out_wb, 640, sa_out_b, x_seq, 640, nullptr, 8192, 640, 640);
    // ---- 4. LN2 + cross-attn (+res) ----
    ln_k<<<2048, 256, 0, stream>>>(x_seq, ln2_s, ln2_b, abuf);
    bgemm_k<EPI_OUT, unsigned short><<<dim3(64, 5), 256, 0, stream>>>(abuf, 640, ca_q_wb, 640, nullptr, u_b, 640, nullptr, 8192, 640, 640);
    bgemm_k<EPI_OUT, unsigned short><<<dim3(5, 5), 256, 0, stream>>>(ctx_b, 512, ca_k_wb, 512, nullptr, kv0, 640, nullptr, 640, 640, 512);
    bgemm_k<EPI_OUT, unsigned short><<<dim3(5, 5), 256, 0, stream>>>(ctx_b, 512, ca_v_wb, 512, nullptr, kv1, 640, nullptr, 640, 640, 512);
    attn_k<<<dim3(32, 8, 8), 256, 0, stream>>>(u_b, 640, kv0, 640, kv1, 640, abuf, 640, 1024, 77, scale);
    bgemm_k<EPI_RES, float><<<dim3(64, 5), 256, 0, stream>>>(abuf, 640, ca_out_wb, 640, ca_out_b, x_seq, 640, nullptr, 8192, 640, 640);
    // ---- 5. LN3 + GeGLU FFN (+res), two M-halves ----
    ln_k<<<2048, 256, 0, stream>>>(x_seq, ln3_s, ln3_b, abuf);
    for (int hhalf = 0; hhalf < 2; ++hhalf) {
        const unsigned short* Ah = abuf + (size_t)hhalf * 4096 * 640;
        bgemm_k<EPI_OUT, float><<<dim3(32, 20), 256, 0, stream>>>(Ah, 640, lin1_wb, 640, lin1_b, u_f, 2560, nullptr, 4096, 2560, 640);
        bgemm_k<EPI_GEGLU, unsigned short><<<dim3(32, 20), 256, 0, stream>>>(Ah, 640, lin1_wb + 2560 * 640, 640, lin1_b + 2560, h_b, 2560, u_f, 4096, 2560, 640);
        bgemm_k<EPI_RES, float><<<dim3(32, 5), 256, 0, stream>>>(h_b, 2560, lin2_wb, 2560, lin2_b, x_seq + (size_t)hhalf * 4096 * 640, 640, nullptr, 4096, 640, 2560);
    }
    // ---- 6. final conv1x1 + long residual (transposed write) ----
    acvt_k<<<20480, 256, 0, stream>>>(x_seq, u_b, 5242880);
    bgemm_k<EPI_CONVT, float><<<dim3(64, 5), 256, 0, stream>>>(u_b, 640, co_wb, 640, co_b, out, 0, x, 8192, 640, 640);
}

// Round 3
// 792.303 us; speedup vs baseline: 4.8205x; 2.6169x over previous
//
#include <hip/hip_runtime.h>

// ---------------------------------------------------------------------------
// AttentionBlock (SD-style). Round 3: MFMA flash attention (bf16, online
// softmax in registers, V^T produced by the GEMM epilogue). GEMMs stay on the
// R2 m97-style bf16 MFMA path. Residual stream fp32.
// B=8, C=640, HW=1024, H=8, DH=80, CTX 77x512.
// ---------------------------------------------------------------------------

#define DH 80

typedef __attribute__((ext_vector_type(8))) short bf16x8;
typedef __attribute__((ext_vector_type(4))) float floatx4;

static __device__ __forceinline__ float gelu_f(float x) {
    return 0.5f * x * (1.0f + erff(x * 0.70710678118654752f));
}
static __device__ __forceinline__ unsigned short f2bf(float f) {
    unsigned u = __float_as_uint(f);
    u = (u + 0x7fffu + ((u >> 16) & 1u)) >> 16;
    return (unsigned short)u;
}
static __device__ __forceinline__ float bf2f(unsigned short s) {
    return __uint_as_float(((unsigned)s) << 16);
}
static __device__ __forceinline__ void async_copy16(const void* g, void* l) {
    __builtin_amdgcn_global_load_lds(
        (const __attribute__((address_space(1))) unsigned int*)g,
        (__attribute__((address_space(3))) unsigned int*)l, 16, 0, 0);
}

// ------------------------- GroupNorm stats ---------------------------------
__global__ __launch_bounds__(256) void gn_stats_k(const float* __restrict__ x,
                                                  float* __restrict__ stats) {
    const int ng = blockIdx.x;                       // n*32 + g
    const float4* base = (const float4*)(x + (size_t)ng * 20480);
    float s = 0.f, s2 = 0.f;
    for (int i = threadIdx.x; i < 5120; i += 256) {
        float4 v = base[i];
        s  += v.x + v.y + v.z + v.w;
        s2 += v.x*v.x + v.y*v.y + v.z*v.z + v.w*v.w;
    }
    for (int m = 1; m < 64; m <<= 1) { s += __shfl_xor(s, m); s2 += __shfl_xor(s2, m); }
    __shared__ float rs[4], rs2[4];
    if ((threadIdx.x & 63) == 0) { rs[threadIdx.x >> 6] = s; rs2[threadIdx.x >> 6] = s2; }
    __syncthreads();
    if (threadIdx.x == 0) {
        float ts = rs[0] + rs[1] + rs[2] + rs[3];
        float t2 = rs2[0] + rs2[1] + rs2[2] + rs2[3];
        float mu = ts * (1.f / 20480.f);
        float var = t2 * (1.f / 20480.f) - mu * mu;
        stats[ng * 2]     = mu;
        stats[ng * 2 + 1] = rsqrtf(var + 1e-6f);
    }
}

// ----------------- GroupNorm apply + transpose, bf16 out --------------------
__global__ __launch_bounds__(256) void gn_apply_t_k(const float* __restrict__ x,
                                                    const float* __restrict__ stats,
                                                    const float* __restrict__ gs,
                                                    const float* __restrict__ gb,
                                                    unsigned short* __restrict__ out) {
    const int p0 = blockIdx.x * 32, c0 = blockIdx.y * 32, n = blockIdx.z;
    __shared__ float tile[32][33];
    const int t = threadIdx.x;
    {
        const int cl = t >> 5, pl = t & 31;
#pragma unroll
        for (int i = 0; i < 4; ++i) {
            int c = c0 + cl + i * 8;
            int g = c / 20;
            float mu = stats[(n * 32 + g) * 2];
            float rstd = stats[(n * 32 + g) * 2 + 1];
            float v = x[(size_t)n * 655360 + (size_t)c * 1024 + p0 + pl];
            tile[cl + i * 8][pl] = (v - mu) * rstd * gs[c] + gb[c];
        }
    }
    __syncthreads();
    {
        const int pl = t >> 5, cl = t & 31;
#pragma unroll
        for (int i = 0; i < 4; ++i) {
            int p = p0 + pl + i * 8;
            out[((size_t)n * 1024 + p) * 640 + c0 + cl] = f2bf(tile[cl][pl + i * 8]);
        }
    }
}

// --------------------------- LayerNorm, bf16 out ----------------------------
__global__ __launch_bounds__(256) void ln_k(const float* __restrict__ x,
                                            const float* __restrict__ g,
                                            const float* __restrict__ b,
                                            unsigned short* __restrict__ o) {
    const int row = blockIdx.x * 4 + (threadIdx.x >> 6);
    const int lane = threadIdx.x & 63;
    const float* xr = x + (size_t)row * 640;
    float v[10];
    float s = 0.f, s2 = 0.f;
#pragma unroll
    for (int i = 0; i < 10; ++i) {
        v[i] = xr[lane + i * 64];
        s += v[i]; s2 += v[i] * v[i];
    }
    for (int m = 1; m < 64; m <<= 1) { s += __shfl_xor(s, m); s2 += __shfl_xor(s2, m); }
    float mu = s * (1.f / 640.f);
    float var = s2 * (1.f / 640.f) - mu * mu;
    float r = rsqrtf(var + 1e-5f);
    unsigned short* orow = o + (size_t)row * 640;
#pragma unroll
    for (int i = 0; i < 10; ++i) {
        int c = lane + i * 64;
        orow[c] = f2bf((v[i] - mu) * r * g[c] + b[c]);
    }
}

// -------------------- weight prep: fp32 -> bf16 -----------------------------
__global__ __launch_bounds__(256) void wcvt_k(const float* __restrict__ W,
                                              unsigned short* __restrict__ O, int n) {
    int i = blockIdx.x * 256 + threadIdx.x;
    if (i < n) O[i] = f2bf(W[i]);
}
// [K][N] fp32 -> [N][K] bf16
__global__ __launch_bounds__(256) void wtr_k(const float* __restrict__ W, int K, int N,
                                             unsigned short* __restrict__ O) {
    __shared__ float tile[32][33];
    const int k0 = blockIdx.x * 32, n0 = blockIdx.y * 32;
    const int tr = threadIdx.x >> 5, tc = threadIdx.x & 31;
#pragma unroll
    for (int i = 0; i < 4; ++i)
        tile[tr + i * 8][tc] = W[(size_t)(k0 + tr + i * 8) * N + n0 + tc];
    __syncthreads();
#pragma unroll
    for (int i = 0; i < 4; ++i)
        O[(size_t)(n0 + tr + i * 8) * K + k0 + tc] = f2bf(tile[tc][tr + i * 8]);
}
// ctx [616][512] fp32 -> [640][512] bf16 zero-padded
__global__ __launch_bounds__(256) void ctxcvt_k(const float* __restrict__ ctx,
                                                unsigned short* __restrict__ O) {
    int i = blockIdx.x * 256 + threadIdx.x;
    if (i < 640 * 512) {
        int r = i >> 9;
        O[i] = (r < 616) ? f2bf(ctx[i]) : (unsigned short)0;
    }
}

// fp32 -> bf16 elementwise (activation copies)
__global__ __launch_bounds__(256) void acvt_k(const float* __restrict__ X,
                                              unsigned short* __restrict__ O, int n) {
    int i = blockIdx.x * 256 + threadIdx.x;
    if (i < n) O[i] = f2bf(X[i]);
}

// --------------------------- bf16 MFMA GEMM ---------------------------------
// C[M,N] = A[M,K] * B^T[N,K] (+bias, epilogue). M%128==0, N%128==0, K%32==0.
enum { EPI_OUT = 0, EPI_RES = 1, EPI_GEGLU = 2, EPI_CONVT = 3, EPI_VT = 4 };

template <int EPI, typename CT>
__global__ __launch_bounds__(256) void bgemm_k(const unsigned short* __restrict__ A, int lda,
                                               const unsigned short* __restrict__ B, int ldb,
                                               const float* __restrict__ bias,
                                               CT* __restrict__ C, int ldc,
                                               const float* __restrict__ aux,
                                               int M, int N, int K,
                                               int sdiv, int spad, int mvalid) {
    __shared__ __attribute__((aligned(16))) short As[128 * 32];
    __shared__ __attribute__((aligned(16))) short Bs[128 * 32];
    const int t = threadIdx.x;
    const int lane = t & 63;
    const int w = __builtin_amdgcn_readfirstlane(t >> 6);
    const int m0 = blockIdx.x * 128, n0 = blockIdx.y * 128;
    const int wm = (w >> 1) * 64, wn = (w & 1) * 64;

    const int sr = lane >> 2;
    const int sc = (lane & 3) * 8;
    const int fm = lane & 15;
    const int fq = (lane >> 4) * 8;

    floatx4 acc[4][4];
#pragma unroll
    for (int i = 0; i < 4; ++i)
#pragma unroll
        for (int j = 0; j < 4; ++j) acc[i][j] = (floatx4){0.f, 0.f, 0.f, 0.f};

    for (int k0 = 0; k0 < K; k0 += 32) {
        const unsigned short* a0 = A + (size_t)(m0 + w * 16 + sr) * lda + k0 + sc;
        const unsigned short* b0 = B + (size_t)(n0 + w * 16 + sr) * ldb + k0 + sc;
        async_copy16(a0,                 As + (w * 16) * 32);
        async_copy16(a0 + (size_t)64 * lda, As + (64 + w * 16) * 32);
        async_copy16(b0,                 Bs + (w * 16) * 32);
        async_copy16(b0 + (size_t)64 * ldb, Bs + (64 + w * 16) * 32);
        __syncthreads();
        bf16x8 af[4], bfr[4];
#pragma unroll
        for (int i = 0; i < 4; ++i) {
            af[i]  = *(const bf16x8*)(As + (wm + i * 16 + fm) * 32 + fq);
            bfr[i] = *(const bf16x8*)(Bs + (wn + i * 16 + fm) * 32 + fq);
        }
#pragma unroll
        for (int i = 0; i < 4; ++i)
#pragma unroll
            for (int j = 0; j < 4; ++j)
                acc[i][j] = __builtin_amdgcn_mfma_f32_16x16x32_bf16(af[i], bfr[j], acc[i][j], 0, 0, 0);
        __syncthreads();
    }

    float bv[4];
#pragma unroll
    for (int j = 0; j < 4; ++j) bv[j] = bias ? bias[n0 + wn + j * 16 + fm] : 0.f;
    const int rbase = (lane >> 4) * 4;

#pragma unroll
    for (int i = 0; i < 4; ++i) {
#pragma unroll
        for (int j = 0; j < 4; ++j) {
            const int n = n0 + wn + j * 16 + fm;
#pragma unroll
            for (int r = 0; r < 4; ++r) {
                const int m = m0 + wm + i * 16 + rbase + r;
                float v = acc[i][j][r] + bv[j];
                if constexpr (EPI == EPI_OUT) {
                    if constexpr (__is_same(CT, float)) {
                        C[(size_t)m * ldc + n] = v;
                    } else {
                        C[(size_t)m * ldc + n] = f2bf(v);
                    }
                } else if constexpr (EPI == EPI_RES) {
                    C[(size_t)m * ldc + n] += v;
                } else if constexpr (EPI == EPI_GEGLU) {
                    float a = aux[(size_t)m * ldc + n];
                    C[(size_t)m * ldc + n] = f2bf(a * gelu_f(v));
                } else if constexpr (EPI == EPI_CONVT) {
                    const int bch = m >> 10, p = m & 1023;
                    const size_t idx = (size_t)bch * 655360 + (size_t)n * 1024 + p;
                    C[idx] = v + aux[idx];
                } else {  // EPI_VT: V^T scatter [(b*8+h)*80+d][spad]
                    if (m < mvalid) {
                        int bb = m / sdiv, s = m - bb * sdiv;
                        int hh = n / 80, d = n - hh * 80;
                        C[((size_t)(bb * 8 + hh) * 80 + d) * spad + s] = f2bf(v);
                    }
                }
            }
        }
    }
}

// -------------------- MFMA flash attention (bf16) ---------------------------
// Block: 64 q-rows of one (b,h); 4 waves x 16 q-rows. BK=64 per iter.
// Q/K read from row-major [token][*stride] at col h*80; V from V^T
// [(b*8+h)*80+d][spad]. DH=80 padded to 96 for K-dim of QK^T.
__global__ __launch_bounds__(256) void mattn_k(const unsigned short* __restrict__ Qp, int qstride,
                                               const unsigned short* __restrict__ Kp, int kstride,
                                               const unsigned short* __restrict__ Vt, int spad,
                                               unsigned short* __restrict__ Op, int ostride,
                                               int sq, int sk, float scale) {
    __shared__ __attribute__((aligned(16))) short Ks[64 * 104];  // [64 k][96+8 pad]
    __shared__ __attribute__((aligned(16))) short Vs[80 * 72];   // [80 d][64+8 pad]
    __shared__ __attribute__((aligned(16))) short Ps[64 * 72];   // [64 q][64+8 pad]

    const int t = threadIdx.x;
    const int lane = t & 63;
    const int w = t >> 6;
    const int fm = lane & 15;
    const int quad = lane >> 4;
    const int b = blockIdx.z, h = blockIdx.y;
    const int q0 = blockIdx.x * 64;

    // Q fragments from global (wave's 16 q-rows), zero-padded to k=96
    bf16x8 qf[3];
    {
        const unsigned short* qbase =
            Qp + (size_t)(b * sq + q0 + w * 16 + fm) * qstride + h * DH;
        qf[0] = *(const bf16x8*)(qbase + quad * 8);
        qf[1] = *(const bf16x8*)(qbase + 32 + quad * 8);
        bf16x8 z = {0, 0, 0, 0, 0, 0, 0, 0};
        qf[2] = (quad < 2) ? *(const bf16x8*)(qbase + 64 + quad * 8) : z;
    }

    float mrow[4], lrow[4];
    floatx4 oacc[5];
#pragma unroll
    for (int r = 0; r < 4; ++r) { mrow[r] = -1e30f; lrow[r] = 0.f; }
#pragma unroll
    for (int d = 0; d < 5; ++d) oacc[d] = (floatx4){0.f, 0.f, 0.f, 0.f};

    const int nkt = (sk + 63) >> 6;
    for (int kt = 0; kt < nkt; ++kt) {
        __syncthreads();  // prior iter's LDS readers done
        // ---- stage K tile [64][96] (zero-pad cols 80..95, mask rows>=sk) ----
        {
            const int tr = t >> 2, tc = t & 3;
            const int kr = kt * 64 + tr;
            const bool ok = kr < sk;
            const unsigned short* krow = Kp + (size_t)(b * sk + kr) * kstride + h * DH;
#pragma unroll
            for (int i = 0; i < 5; ++i) {
                const int col = tc * 4 + i * 16;
                ushort4 v = make_ushort4(0, 0, 0, 0);
                if (ok) v = *(const ushort4*)(krow + col);
                *(ushort4*)(Ks + tr * 104 + col) = v;
            }
            *(ushort4*)(Ks + tr * 104 + 80 + tc * 4) = make_ushort4(0, 0, 0, 0);
        }
        // ---- stage V^T tile [80][64] ----
        {
            const unsigned short* vbase = Vt + ((size_t)(b * 8 + h) * 80) * spad + kt * 64;
#pragma unroll
            for (int i = 0; i < 5; ++i) {
                const int lin = t + i * 256;       // 0..1279
                const int row = lin >> 4;          // 0..79
                const int colq = (lin & 15) * 4;   // 0..60
                ushort4 v = *(const ushort4*)(vbase + (size_t)row * spad + colq);
                *(ushort4*)(Vs + row * 72 + colq) = v;
            }
        }
        __syncthreads();

        // ---- S = Q K^T for this wave's 16 q-rows x 64 k ----
        floatx4 sacc[4];
#pragma unroll
        for (int j = 0; j < 4; ++j) sacc[j] = (floatx4){0.f, 0.f, 0.f, 0.f};
#pragma unroll
        for (int c = 0; c < 3; ++c) {
#pragma unroll
            for (int j = 0; j < 4; ++j) {
                bf16x8 kf = *(const bf16x8*)(Ks + (j * 16 + fm) * 104 + c * 32 + quad * 8);
                sacc[j] = __builtin_amdgcn_mfma_f32_16x16x32_bf16(qf[c], kf, sacc[j], 0, 0, 0);
            }
        }

        // ---- online softmax in registers ----
        float p[4][4];  // [k-tile j][row r]
#pragma unroll
        for (int j = 0; j < 4; ++j) {
            const bool msk = (kt * 64 + j * 16 + fm) >= sk;
#pragma unroll
            for (int r = 0; r < 4; ++r)
                p[j][r] = msk ? -1e30f : sacc[j][r] * scale;
        }
        float alpha[4];
#pragma unroll
        for (int r = 0; r < 4; ++r) {
            float mx = fmaxf(fmaxf(p[0][r], p[1][r]), fmaxf(p[2][r], p[3][r]));
#pragma unroll
            for (int d = 1; d < 16; d <<= 1) mx = fmaxf(mx, __shfl_xor(mx, d));
            const float mn = fmaxf(mrow[r], mx);
            alpha[r] = __expf(mrow[r] - mn);
            float rs = 0.f;
#pragma unroll
            for (int j = 0; j < 4; ++j) { p[j][r] = __expf(p[j][r] - mn); rs += p[j][r]; }
#pragma unroll
            for (int d = 1; d < 16; d <<= 1) rs += __shfl_xor(rs, d);
            lrow[r] = lrow[r] * alpha[r] + rs;
            mrow[r] = mn;
        }
#pragma unroll
        for (int d = 0; d < 5; ++d)
#pragma unroll
            for (int r = 0; r < 4; ++r) oacc[d][r] *= alpha[r];

        // ---- P: C-layout -> LDS (A-layout round trip) ----
#pragma unroll
        for (int j = 0; j < 4; ++j)
#pragma unroll
            for (int r = 0; r < 4; ++r)
                Ps[(w * 16 + quad * 4 + r) * 72 + j * 16 + fm] = f2bf(p[j][r]);
        __syncthreads();

        // ---- O += P V ----
        bf16x8 pf0 = *(const bf16x8*)(Ps + (w * 16 + fm) * 72 + quad * 8);
        bf16x8 pf1 = *(const bf16x8*)(Ps + (w * 16 + fm) * 72 + 32 + quad * 8);
#pragma unroll
        for (int d = 0; d < 5; ++d) {
            bf16x8 vf0 = *(const bf16x8*)(Vs + (d * 16 + fm) * 72 + quad * 8);
            bf16x8 vf1 = *(const bf16x8*)(Vs + (d * 16 + fm) * 72 + 32 + quad * 8);
            oacc[d] = __builtin_amdgcn_mfma_f32_16x16x32_bf16(pf0, vf0, oacc[d], 0, 0, 0);
            oacc[d] = __builtin_amdgcn_mfma_f32_16x16x32_bf16(pf1, vf1, oacc[d], 0, 0, 0);
        }
    }

    // ---- epilogue: O / l, write bf16 ----
    unsigned short* obase = Op + (size_t)(b * sq + q0 + w * 16) * ostride + h * DH;
#pragma unroll
    for (int r = 0; r < 4; ++r) {
        const float inv = 1.f / lrow[r];
#pragma unroll
        for (int d = 0; d < 5; ++d)
            obase[(size_t)(quad * 4 + r) * ostride + d * 16 + fm] = f2bf(oacc[d][r] * inv);
    }
}

// ---------------------------------------------------------------------------
extern "C" void kernel_launch(void* const* d_in, const int* in_sizes, int n_in,
                              void* d_out, int out_size, void* d_ws, size_t ws_size,
                              hipStream_t stream) {
    const float* x        = (const float*)d_in[0];
    const float* ctx      = (const float*)d_in[1];
    const float* gn_s     = (const float*)d_in[2];
    const float* gn_b     = (const float*)d_in[3];
    const float* conv1_w  = (const float*)d_in[4];
    const float* conv1_b  = (const float*)d_in[5];
    const float* ln1_s    = (const float*)d_in[6];
    const float* ln1_b    = (const float*)d_in[7];
    const float* sa_in_w  = (const float*)d_in[8];
    const float* sa_out_w = (const float*)d_in[9];
    const float* sa_out_b = (const float*)d_in[10];
    const float* ln2_s    = (const float*)d_in[11];
    const float* ln2_b    = (const float*)d_in[12];
    const float* ca_q_w   = (const float*)d_in[13];
    const float* ca_k_w   = (const float*)d_in[14];
    const float* ca_v_w   = (const float*)d_in[15];
    const float* ca_out_w = (const float*)d_in[16];
    const float* ca_out_b = (const float*)d_in[17];
    const float* ln3_s    = (const float*)d_in[18];
    const float* ln3_b    = (const float*)d_in[19];
    const float* lin1_w   = (const float*)d_in[20];
    const float* lin1_b   = (const float*)d_in[21];
    const float* lin2_w   = (const float*)d_in[22];
    const float* lin2_b   = (const float*)d_in[23];
    const float* co_w     = (const float*)d_in[24];
    const float* co_b     = (const float*)d_in[25];

    float* out = (float*)d_out;       // doubles as x_seq (fp32 residual stream)
    float* ws = (float*)d_ws;
    float* x_seq = out;

    // ws layout (float units)
    float* u_f = ws;                                   // [4096][2560] fp32 FFN a-half; overlaid: qk_b / q_b bf16
    unsigned short* qk_b  = (unsigned short*)ws;       // self qk bf16 [8192][1280]; cross q [8192][640]
    unsigned short* h_b   = (unsigned short*)(ws + 10485760);  // [4096][2560] bf16
    unsigned short* abuf  = (unsigned short*)(ws + 15728640);  // [8192][640] bf16
    unsigned short* kv0   = (unsigned short*)(ws + 18350080);  // [640][640] bf16 (cross K)
    unsigned short* vT_s  = (unsigned short*)(ws + 18554880);  // [64*80][1024] bf16 (self V^T)
    unsigned short* vT_c  = (unsigned short*)(ws + 21176320);  // [64*80][128] bf16 (cross V^T)
    unsigned short* ctx_b = (unsigned short*)(ws + 21504000);  // [640][512] bf16
    size_t woff = 21667840;
    unsigned short* conv1_wb  = (unsigned short*)(ws + woff); woff += 204800;
    unsigned short* sa_in_wb  = (unsigned short*)(ws + woff); woff += 614400;
    unsigned short* sa_out_wb = (unsigned short*)(ws + woff); woff += 204800;
    unsigned short* ca_q_wb   = (unsigned short*)(ws + woff); woff += 204800;
    unsigned short* ca_k_wb   = (unsigned short*)(ws + woff); woff += 163840;
    unsigned short* ca_v_wb   = (unsigned short*)(ws + woff); woff += 163840;
    unsigned short* ca_out_wb = (unsigned short*)(ws + woff); woff += 204800;
    unsigned short* lin1_wb   = (unsigned short*)(ws + woff); woff += 1638400;
    unsigned short* lin2_wb   = (unsigned short*)(ws + woff); woff += 819200;
    unsigned short* co_wb     = (unsigned short*)(ws + woff); woff += 204800;
    float* stats = ws + woff;

    const float scale = 0.11180339887498949f;  // 1/sqrt(80)

    // ---- weight prep (same work every call; graph-safe) ----
    wcvt_k<<<1600, 256, 0, stream>>>(conv1_w, conv1_wb, 409600);
    wcvt_k<<<1600, 256, 0, stream>>>(co_w, co_wb, 409600);
    ctxcvt_k<<<1280, 256, 0, stream>>>(ctx, ctx_b);
    wtr_k<<<dim3(20, 60), 256, 0, stream>>>(sa_in_w, 640, 1920, sa_in_wb);
    wtr_k<<<dim3(20, 20), 256, 0, stream>>>(sa_out_w, 640, 640, sa_out_wb);
    wtr_k<<<dim3(20, 20), 256, 0, stream>>>(ca_q_w, 640, 640, ca_q_wb);
    wtr_k<<<dim3(16, 20), 256, 0, stream>>>(ca_k_w, 512, 640, ca_k_wb);
    wtr_k<<<dim3(16, 20), 256, 0, stream>>>(ca_v_w, 512, 640, ca_v_wb);
    wtr_k<<<dim3(20, 20), 256, 0, stream>>>(ca_out_w, 640, 640, ca_out_wb);
    wtr_k<<<dim3(20, 160), 256, 0, stream>>>(lin1_w, 640, 5120, lin1_wb);
    wtr_k<<<dim3(80, 20), 256, 0, stream>>>(lin2_w, 2560, 640, lin2_wb);

    // ---- 1. GroupNorm + transpose (bf16) ----
    gn_stats_k<<<256, 256, 0, stream>>>(x, stats);
    gn_apply_t_k<<<dim3(32, 20, 8), 256, 0, stream>>>(x, stats, gn_s, gn_b, abuf);
    // ---- 2. conv1 -> x_seq fp32 ----
    bgemm_k<EPI_OUT, float><<<dim3(64, 5), 256, 0, stream>>>(abuf, 640, conv1_wb, 640, conv1_b, x_seq, 640, nullptr, 8192, 640, 640, 0, 0, 0);
    // ---- 3. LN1 + QKV + self-attn + out-proj (+res) ----
    ln_k<<<2048, 256, 0, stream>>>(x_seq, ln1_s, ln1_b, abuf);
    bgemm_k<EPI_OUT, unsigned short><<<dim3(64, 10), 256, 0, stream>>>(abuf, 640, sa_in_wb, 640, nullptr, qk_b, 1280, nullptr, 8192, 1280, 640, 0, 0, 0);
    bgemm_k<EPI_VT, unsigned short><<<dim3(64, 5), 256, 0, stream>>>(abuf, 640, sa_in_wb + (size_t)1280 * 640, 640, nullptr, vT_s, 0, nullptr, 8192, 640, 640, 1024, 1024, 8192);
    mattn_k<<<dim3(16, 8, 8), 256, 0, stream>>>(qk_b, 1280, qk_b + 640, 1280, vT_s, 1024, abuf, 640, 1024, 1024, scale);
    bgemm_k<EPI_RES, float><<<dim3(64, 5), 256, 0, stream>>>(abuf, 640, sa_out_wb, 640, sa_out_b, x_seq, 640, nullptr, 8192, 640, 640, 0, 0, 0);
    // ---- 4. LN2 + cross-attn (+res) ----
    ln_k<<<2048, 256, 0, stream>>>(x_seq, ln2_s, ln2_b, abuf);
    bgemm_k<EPI_OUT, unsigned short><<<dim3(64, 5), 256, 0, stream>>>(abuf, 640, ca_q_wb, 640, nullptr, qk_b, 640, nullptr, 8192, 640, 640, 0, 0, 0);
    bgemm_k<EPI_OUT, unsigned short><<<dim3(5, 5), 256, 0, stream>>>(ctx_b, 512, ca_k_wb, 512, nullptr, kv0, 640, nullptr, 640, 640, 512, 0, 0, 0);
    bgemm_k<EPI_VT, unsigned short><<<dim3(5, 5), 256, 0, stream>>>(ctx_b, 512, ca_v_wb, 512, nullptr, vT_c, 0, nullptr, 640, 640, 512, 77, 128, 616);
    mattn_k<<<dim3(16, 8, 8), 256, 0, stream>>>(qk_b, 640, kv0, 640, vT_c, 128, abuf, 640, 1024, 77, scale);
    bgemm_k<EPI_RES, float><<<dim3(64, 5), 256, 0, stream>>>(abuf, 640, ca_out_wb, 640, ca_out_b, x_seq, 640, nullptr, 8192, 640, 640, 0, 0, 0);
    // ---- 5. LN3 + GeGLU FFN (+res), two M-halves ----
    ln_k<<<2048, 256, 0, stream>>>(x_seq, ln3_s, ln3_b, abuf);
    for (int hhalf = 0; hhalf < 2; ++hhalf) {
        const unsigned short* Ah = abuf + (size_t)hhalf * 4096 * 640;
        bgemm_k<EPI_OUT, float><<<dim3(32, 20), 256, 0, stream>>>(Ah, 640, lin1_wb, 640, lin1_b, u_f, 2560, nullptr, 4096, 2560, 640, 0, 0, 0);
        bgemm_k<EPI_GEGLU, unsigned short><<<dim3(32, 20), 256, 0, stream>>>(Ah, 640, lin1_wb + (size_t)2560 * 640, 640, lin1_b + 2560, h_b, 2560, u_f, 4096, 2560, 640, 0, 0, 0);
        bgemm_k<EPI_RES, float><<<dim3(32, 5), 256, 0, stream>>>(h_b, 2560, lin2_wb, 2560, lin2_b, x_seq + (size_t)hhalf * 4096 * 640, 640, nullptr, 4096, 640, 2560, 0, 0, 0);
    }
    // ---- 6. final conv1x1 + long residual (transposed write) ----
    acvt_k<<<20480, 256, 0, stream>>>(x_seq, qk_b, 5242880);
    bgemm_k<EPI_CONVT, float><<<dim3(64, 5), 256, 0, stream>>>(qk_b, 640, co_wb, 640, co_b, out, 0, x, 8192, 640, 640, 0, 0, 0);
}

// Round 4
// 662.640 us; speedup vs baseline: 5.7638x; 1.1957x over previous
//
#include <hip/hip_runtime.h>

// ---------------------------------------------------------------------------
// AttentionBlock (SD-style). Round 4:
//  - mattn_k computes S^T (swap MFMA operands) -> softmax rows live per-lane:
//    8 shuffles/iter instead of 32, P written as ds_write_b64 x4 not b16 x16.
//  - lin1 a+gate fused dual-B GeGLU GEMM (no fp32 intermediate).
//  - qkv+V^T one dispatch; cross q/k/v one dispatch; weight prep 2 launches.
// B=8, C=640, HW=1024, H=8, DH=80, CTX 77x512.
// ---------------------------------------------------------------------------

#define DH 80

typedef __attribute__((ext_vector_type(8))) short bf16x8;
typedef __attribute__((ext_vector_type(4))) float floatx4;

static __device__ __forceinline__ float gelu_f(float x) {
    return 0.5f * x * (1.0f + erff(x * 0.70710678118654752f));
}
static __device__ __forceinline__ unsigned short f2bf(float f) {
    unsigned u = __float_as_uint(f);
    u = (u + 0x7fffu + ((u >> 16) & 1u)) >> 16;
    return (unsigned short)u;
}
static __device__ __forceinline__ void async_copy16(const void* g, void* l) {
    __builtin_amdgcn_global_load_lds(
        (const __attribute__((address_space(1))) unsigned int*)g,
        (__attribute__((address_space(3))) unsigned int*)l, 16, 0, 0);
}

// ------------------------- GroupNorm stats ---------------------------------
__global__ __launch_bounds__(256) void gn_stats_k(const float* __restrict__ x,
                                                  float* __restrict__ stats) {
    const int ng = blockIdx.x;                       // n*32 + g
    const float4* base = (const float4*)(x + (size_t)ng * 20480);
    float s = 0.f, s2 = 0.f;
    for (int i = threadIdx.x; i < 5120; i += 256) {
        float4 v = base[i];
        s  += v.x + v.y + v.z + v.w;
        s2 += v.x*v.x + v.y*v.y + v.z*v.z + v.w*v.w;
    }
    for (int m = 1; m < 64; m <<= 1) { s += __shfl_xor(s, m); s2 += __shfl_xor(s2, m); }
    __shared__ float rs[4], rs2[4];
    if ((threadIdx.x & 63) == 0) { rs[threadIdx.x >> 6] = s; rs2[threadIdx.x >> 6] = s2; }
    __syncthreads();
    if (threadIdx.x == 0) {
        float ts = rs[0] + rs[1] + rs[2] + rs[3];
        float t2 = rs2[0] + rs2[1] + rs2[2] + rs2[3];
        float mu = ts * (1.f / 20480.f);
        float var = t2 * (1.f / 20480.f) - mu * mu;
        stats[ng * 2]     = mu;
        stats[ng * 2 + 1] = rsqrtf(var + 1e-6f);
    }
}

// ----------------- GroupNorm apply + transpose, bf16 out --------------------
__global__ __launch_bounds__(256) void gn_apply_t_k(const float* __restrict__ x,
                                                    const float* __restrict__ stats,
                                                    const float* __restrict__ gs,
                                                    const float* __restrict__ gb,
                                                    unsigned short* __restrict__ out) {
    const int p0 = blockIdx.x * 32, c0 = blockIdx.y * 32, n = blockIdx.z;
    __shared__ float tile[32][33];
    const int t = threadIdx.x;
    {
        const int cl = t >> 5, pl = t & 31;
#pragma unroll
        for (int i = 0; i < 4; ++i) {
            int c = c0 + cl + i * 8;
            int g = c / 20;
            float mu = stats[(n * 32 + g) * 2];
            float rstd = stats[(n * 32 + g) * 2 + 1];
            float v = x[(size_t)n * 655360 + (size_t)c * 1024 + p0 + pl];
            tile[cl + i * 8][pl] = (v - mu) * rstd * gs[c] + gb[c];
        }
    }
    __syncthreads();
    {
        const int pl = t >> 5, cl = t & 31;
#pragma unroll
        for (int i = 0; i < 4; ++i) {
            int p = p0 + pl + i * 8;
            out[((size_t)n * 1024 + p) * 640 + c0 + cl] = f2bf(tile[cl][pl + i * 8]);
        }
    }
}

// --------------------------- LayerNorm, bf16 out ----------------------------
__global__ __launch_bounds__(256) void ln_k(const float* __restrict__ x,
                                            const float* __restrict__ g,
                                            const float* __restrict__ b,
                                            unsigned short* __restrict__ o) {
    const int row = blockIdx.x * 4 + (threadIdx.x >> 6);
    const int lane = threadIdx.x & 63;
    const float* xr = x + (size_t)row * 640;
    float v[10];
    float s = 0.f, s2 = 0.f;
#pragma unroll
    for (int i = 0; i < 10; ++i) {
        v[i] = xr[lane + i * 64];
        s += v[i]; s2 += v[i] * v[i];
    }
    for (int m = 1; m < 64; m <<= 1) { s += __shfl_xor(s, m); s2 += __shfl_xor(s2, m); }
    float mu = s * (1.f / 640.f);
    float var = s2 * (1.f / 640.f) - mu * mu;
    float r = rsqrtf(var + 1e-5f);
    unsigned short* orow = o + (size_t)row * 640;
#pragma unroll
    for (int i = 0; i < 10; ++i) {
        int c = lane + i * 64;
        orow[c] = f2bf((v[i] - mu) * r * g[c] + b[c]);
    }
}

// ---------------- merged weight prep: all [K][N]->[N][K] transposes ---------
__global__ __launch_bounds__(256) void prep_tr_k(
        const float* __restrict__ sa_in_w,  unsigned short* __restrict__ sa_in_wb,
        const float* __restrict__ sa_out_w, unsigned short* __restrict__ sa_out_wb,
        const float* __restrict__ ca_q_w,   unsigned short* __restrict__ ca_q_wb,
        const float* __restrict__ ca_k_w,   unsigned short* __restrict__ ca_k_wb,
        const float* __restrict__ ca_v_w,   unsigned short* __restrict__ ca_v_wb,
        const float* __restrict__ ca_out_w, unsigned short* __restrict__ ca_out_wb,
        const float* __restrict__ lin1_w,   unsigned short* __restrict__ lin1_wb,
        const float* __restrict__ lin2_w,   unsigned short* __restrict__ lin2_wb) {
    const int bid = blockIdx.x;
    int r; const float* W; unsigned short* O; int K, N;
    if (bid < 1200)      { r = bid;        W = sa_in_w;  O = sa_in_wb;  K = 640;  N = 1920; }
    else if (bid < 1600) { r = bid - 1200; W = sa_out_w; O = sa_out_wb; K = 640;  N = 640;  }
    else if (bid < 2000) { r = bid - 1600; W = ca_q_w;   O = ca_q_wb;   K = 640;  N = 640;  }
    else if (bid < 2320) { r = bid - 2000; W = ca_k_w;   O = ca_k_wb;   K = 512;  N = 640;  }
    else if (bid < 2640) { r = bid - 2320; W = ca_v_w;   O = ca_v_wb;   K = 512;  N = 640;  }
    else if (bid < 3040) { r = bid - 2640; W = ca_out_w; O = ca_out_wb; K = 640;  N = 640;  }
    else if (bid < 6240) { r = bid - 3040; W = lin1_w;   O = lin1_wb;   K = 640;  N = 5120; }
    else                 { r = bid - 6240; W = lin2_w;   O = lin2_wb;   K = 2560; N = 640;  }
    const int tX = K >> 5;
    const int k0 = (r % tX) * 32, n0 = (r / tX) * 32;
    __shared__ float tile[32][33];
    const int tr = threadIdx.x >> 5, tc = threadIdx.x & 31;
#pragma unroll
    for (int i = 0; i < 4; ++i)
        tile[tr + i * 8][tc] = W[(size_t)(k0 + tr + i * 8) * N + n0 + tc];
    __syncthreads();
#pragma unroll
    for (int i = 0; i < 4; ++i)
        O[(size_t)(n0 + tr + i * 8) * K + k0 + tc] = f2bf(tile[tc][tr + i * 8]);
}

// ------- merged elementwise prep: conv1/co cvt, ctx pad-cvt, zero vT_c ------
__global__ __launch_bounds__(256) void prep_ew_k(const float* __restrict__ w1,
                                                 unsigned short* __restrict__ c1,
                                                 const float* __restrict__ w2,
                                                 unsigned short* __restrict__ c2,
                                                 const float* __restrict__ ctx,
                                                 unsigned short* __restrict__ cb,
                                                 unsigned int* __restrict__ vtc) {
    const int i = blockIdx.x * 256 + threadIdx.x;
    if (i < 409600) c1[i] = f2bf(w1[i]);
    else if (i < 819200) c2[i - 409600] = f2bf(w2[i - 409600]);
    else if (i < 1146880) {
        const int j = i - 819200;
        const int r = j >> 9;
        cb[j] = (r < 616) ? f2bf(ctx[j]) : (unsigned short)0;
    } else {
        vtc[i - 1146880] = 0u;   // zero cross V^T (masked cols read by attn)
    }
}

// --------------------------- bf16 MFMA GEMM ---------------------------------
// C[M,N] = A[M,K] * B^T[N,K] (+bias, epilogue). M%128==0, N%128==0, K%32==0.
enum { EPI_OUT = 0, EPI_RES = 1, EPI_CONVT = 3, EPI_QKV = 5, EPI_RES_BF = 6 };

template <int EPI, typename CT>
__global__ __launch_bounds__(256) void bgemm_k(const unsigned short* __restrict__ A, int lda,
                                               const unsigned short* __restrict__ B, int ldb,
                                               const float* __restrict__ bias,
                                               CT* __restrict__ C, int ldc,
                                               const float* __restrict__ aux,
                                               unsigned short* __restrict__ extra,
                                               int M, int N, int K) {
    __shared__ __attribute__((aligned(16))) short As[128 * 32];
    __shared__ __attribute__((aligned(16))) short Bs[128 * 32];
    const int t = threadIdx.x;
    const int lane = t & 63;
    const int w = __builtin_amdgcn_readfirstlane(t >> 6);
    const int m0 = blockIdx.x * 128, n0 = blockIdx.y * 128;
    const int wm = (w >> 1) * 64, wn = (w & 1) * 64;

    const int sr = lane >> 2;
    const int sc = (lane & 3) * 8;
    const int fm = lane & 15;
    const int fq = (lane >> 4) * 8;

    floatx4 acc[4][4];
#pragma unroll
    for (int i = 0; i < 4; ++i)
#pragma unroll
        for (int j = 0; j < 4; ++j) acc[i][j] = (floatx4){0.f, 0.f, 0.f, 0.f};

    for (int k0 = 0; k0 < K; k0 += 32) {
        const unsigned short* a0 = A + (size_t)(m0 + w * 16 + sr) * lda + k0 + sc;
        const unsigned short* b0 = B + (size_t)(n0 + w * 16 + sr) * ldb + k0 + sc;
        async_copy16(a0,                    As + (w * 16) * 32);
        async_copy16(a0 + (size_t)64 * lda, As + (64 + w * 16) * 32);
        async_copy16(b0,                    Bs + (w * 16) * 32);
        async_copy16(b0 + (size_t)64 * ldb, Bs + (64 + w * 16) * 32);
        __syncthreads();
        bf16x8 af[4], bfr[4];
#pragma unroll
        for (int i = 0; i < 4; ++i) {
            af[i]  = *(const bf16x8*)(As + (wm + i * 16 + fm) * 32 + fq);
            bfr[i] = *(const bf16x8*)(Bs + (wn + i * 16 + fm) * 32 + fq);
        }
#pragma unroll
        for (int i = 0; i < 4; ++i)
#pragma unroll
            for (int j = 0; j < 4; ++j)
                acc[i][j] = __builtin_amdgcn_mfma_f32_16x16x32_bf16(af[i], bfr[j], acc[i][j], 0, 0, 0);
        __syncthreads();
    }

    float bv[4];
#pragma unroll
    for (int j = 0; j < 4; ++j) bv[j] = bias ? bias[n0 + wn + j * 16 + fm] : 0.f;
    const int rbase = (lane >> 4) * 4;

#pragma unroll
    for (int i = 0; i < 4; ++i) {
#pragma unroll
        for (int j = 0; j < 4; ++j) {
            const int n = n0 + wn + j * 16 + fm;
#pragma unroll
            for (int r = 0; r < 4; ++r) {
                const int m = m0 + wm + i * 16 + rbase + r;
                float v = acc[i][j][r] + bv[j];
                if constexpr (EPI == EPI_OUT) {
                    if constexpr (__is_same(CT, float)) {
                        C[(size_t)m * ldc + n] = v;
                    } else {
                        C[(size_t)m * ldc + n] = f2bf(v);
                    }
                } else if constexpr (EPI == EPI_RES) {
                    C[(size_t)m * ldc + n] += v;
                } else if constexpr (EPI == EPI_RES_BF) {
                    const size_t idx = (size_t)m * ldc + n;
                    float nv = C[idx] + v;
                    C[idx] = nv;
                    extra[idx] = f2bf(nv);
                } else if constexpr (EPI == EPI_CONVT) {
                    const int bch = m >> 10, p = m & 1023;
                    const size_t idx = (size_t)bch * 655360 + (size_t)n * 1024 + p;
                    C[idx] = v + aux[idx];
                } else {  // EPI_QKV: n<1280 -> qk store; else V^T scatter
                    if (n < 1280) {
                        C[(size_t)m * 1280 + n] = f2bf(v);
                    } else {
                        const int nv2 = n - 1280;
                        const int hh = nv2 / 80, d = nv2 - hh * 80;
                        const int bb = m >> 10, s = m & 1023;
                        extra[((size_t)(bb * 8 + hh) * 80 + d) * 1024 + s] = f2bf(v);
                    }
                }
            }
        }
    }
}

// -------- cross-attn projections: q (8192x640) + K,V (640x640) in one -------
__global__ __launch_bounds__(256) void cross_gemms_k(
        const unsigned short* __restrict__ xq, const unsigned short* __restrict__ ctx_b,
        const unsigned short* __restrict__ Wq, const unsigned short* __restrict__ Wk,
        const unsigned short* __restrict__ Wv,
        unsigned short* __restrict__ q_out, unsigned short* __restrict__ k_out,
        unsigned short* __restrict__ vT_out) {
    __shared__ __attribute__((aligned(16))) short As[128 * 32];
    __shared__ __attribute__((aligned(16))) short Bs[128 * 32];
    const int bx = blockIdx.x;
    int job, m0, n0, lda, K;
    const unsigned short *A, *B;
    if (bx < 320)      { job = 0; m0 = (bx & 63) * 128; n0 = (bx >> 6) * 128; A = xq;    B = Wq; lda = 640; K = 640; }
    else if (bx < 345) { int i = bx - 320; job = 1; m0 = (i % 5) * 128; n0 = (i / 5) * 128; A = ctx_b; B = Wk; lda = 512; K = 512; }
    else               { int i = bx - 345; job = 2; m0 = (i % 5) * 128; n0 = (i / 5) * 128; A = ctx_b; B = Wv; lda = 512; K = 512; }

    const int t = threadIdx.x;
    const int lane = t & 63;
    const int w = __builtin_amdgcn_readfirstlane(t >> 6);
    const int wm = (w >> 1) * 64, wn = (w & 1) * 64;
    const int sr = lane >> 2, sc = (lane & 3) * 8;
    const int fm = lane & 15, fq = (lane >> 4) * 8;

    floatx4 acc[4][4];
#pragma unroll
    for (int i = 0; i < 4; ++i)
#pragma unroll
        for (int j = 0; j < 4; ++j) acc[i][j] = (floatx4){0.f, 0.f, 0.f, 0.f};

    for (int k0 = 0; k0 < K; k0 += 32) {
        const unsigned short* a0 = A + (size_t)(m0 + w * 16 + sr) * lda + k0 + sc;
        const unsigned short* b0 = B + (size_t)(n0 + w * 16 + sr) * lda + k0 + sc;
        async_copy16(a0,                    As + (w * 16) * 32);
        async_copy16(a0 + (size_t)64 * lda, As + (64 + w * 16) * 32);
        async_copy16(b0,                    Bs + (w * 16) * 32);
        async_copy16(b0 + (size_t)64 * lda, Bs + (64 + w * 16) * 32);
        __syncthreads();
        bf16x8 af[4], bfr[4];
#pragma unroll
        for (int i = 0; i < 4; ++i) {
            af[i]  = *(const bf16x8*)(As + (wm + i * 16 + fm) * 32 + fq);
            bfr[i] = *(const bf16x8*)(Bs + (wn + i * 16 + fm) * 32 + fq);
        }
#pragma unroll
        for (int i = 0; i < 4; ++i)
#pragma unroll
            for (int j = 0; j < 4; ++j)
                acc[i][j] = __builtin_amdgcn_mfma_f32_16x16x32_bf16(af[i], bfr[j], acc[i][j], 0, 0, 0);
        __syncthreads();
    }

    const int rbase = (lane >> 4) * 4;
#pragma unroll
    for (int i = 0; i < 4; ++i) {
#pragma unroll
        for (int j = 0; j < 4; ++j) {
            const int n = n0 + wn + j * 16 + fm;
#pragma unroll
            for (int r = 0; r < 4; ++r) {
                const int m = m0 + wm + i * 16 + rbase + r;
                const float v = acc[i][j][r];
                if (job == 0) {
                    q_out[(size_t)m * 640 + n] = f2bf(v);
                } else if (job == 1) {
                    k_out[(size_t)m * 640 + n] = f2bf(v);
                } else {
                    if (m < 616) {
                        const int bb = m / 77, s = m - bb * 77;
                        const int hh = n / 80, d = n - hh * 80;
                        vT_out[((size_t)(bb * 8 + hh) * 80 + d) * 128 + s] = f2bf(v);
                    }
                }
            }
        }
    }
}

// ---------------- fused GeGLU lin1: h = a * gelu(gate), dual-B GEMM ---------
__global__ __launch_bounds__(256) void geglu_k(const unsigned short* __restrict__ A,
                                               const unsigned short* __restrict__ B1,
                                               const unsigned short* __restrict__ B2,
                                               const float* __restrict__ bias,  // [5120]
                                               unsigned short* __restrict__ H) {
    __shared__ __attribute__((aligned(16))) short As[128 * 32];
    __shared__ __attribute__((aligned(16))) short B1s[128 * 32];
    __shared__ __attribute__((aligned(16))) short B2s[128 * 32];
    const int t = threadIdx.x;
    const int lane = t & 63;
    const int w = __builtin_amdgcn_readfirstlane(t >> 6);
    const int m0 = blockIdx.x * 128, n0 = blockIdx.y * 128;
    const int wm = (w >> 1) * 64, wn = (w & 1) * 64;
    const int sr = lane >> 2, sc = (lane & 3) * 8;
    const int fm = lane & 15, fq = (lane >> 4) * 8;

    floatx4 aa[4][4], ag[4][4];
#pragma unroll
    for (int i = 0; i < 4; ++i)
#pragma unroll
        for (int j = 0; j < 4; ++j) {
            aa[i][j] = (floatx4){0.f, 0.f, 0.f, 0.f};
            ag[i][j] = (floatx4){0.f, 0.f, 0.f, 0.f};
        }

    for (int k0 = 0; k0 < 640; k0 += 32) {
        const unsigned short* a0 = A  + (size_t)(m0 + w * 16 + sr) * 640 + k0 + sc;
        const unsigned short* b1 = B1 + (size_t)(n0 + w * 16 + sr) * 640 + k0 + sc;
        const unsigned short* b2 = B2 + (size_t)(n0 + w * 16 + sr) * 640 + k0 + sc;
        async_copy16(a0,                    As  + (w * 16) * 32);
        async_copy16(a0 + (size_t)64 * 640, As  + (64 + w * 16) * 32);
        async_copy16(b1,                    B1s + (w * 16) * 32);
        async_copy16(b1 + (size_t)64 * 640, B1s + (64 + w * 16) * 32);
        async_copy16(b2,                    B2s + (w * 16) * 32);
        async_copy16(b2 + (size_t)64 * 640, B2s + (64 + w * 16) * 32);
        __syncthreads();
        bf16x8 af[4], b1f[4], b2f[4];
#pragma unroll
        for (int i = 0; i < 4; ++i) {
            af[i]  = *(const bf16x8*)(As  + (wm + i * 16 + fm) * 32 + fq);
            b1f[i] = *(const bf16x8*)(B1s + (wn + i * 16 + fm) * 32 + fq);
            b2f[i] = *(const bf16x8*)(B2s + (wn + i * 16 + fm) * 32 + fq);
        }
#pragma unroll
        for (int i = 0; i < 4; ++i)
#pragma unroll
            for (int j = 0; j < 4; ++j) {
                aa[i][j] = __builtin_amdgcn_mfma_f32_16x16x32_bf16(af[i], b1f[j], aa[i][j], 0, 0, 0);
                ag[i][j] = __builtin_amdgcn_mfma_f32_16x16x32_bf16(af[i], b2f[j], ag[i][j], 0, 0, 0);
            }
        __syncthreads();
    }

    float bv1[4], bv2[4];
#pragma unroll
    for (int j = 0; j < 4; ++j) {
        bv1[j] = bias[n0 + wn + j * 16 + fm];
        bv2[j] = bias[2560 + n0 + wn + j * 16 + fm];
    }
    const int rbase = (lane >> 4) * 4;
#pragma unroll
    for (int i = 0; i < 4; ++i)
#pragma unroll
        for (int j = 0; j < 4; ++j) {
            const int n = n0 + wn + j * 16 + fm;
#pragma unroll
            for (int r = 0; r < 4; ++r) {
                const int m = m0 + wm + i * 16 + rbase + r;
                const float a = aa[i][j][r] + bv1[j];
                const float g = ag[i][j][r] + bv2[j];
                H[(size_t)m * 2560 + n] = f2bf(a * gelu_f(g));
            }
        }
}

// -------------------- MFMA flash attention (S^T formulation) ----------------
// Block: 64 q-rows of one (b,h); 4 waves x 16 q-rows. BK=64 per iter.
// S^T = K Q^T: C col = q = lane&15 -> softmax rows per-lane (2+2 shuffles).
__global__ __launch_bounds__(256) void mattn_k(const unsigned short* __restrict__ Qp, int qstride,
                                               const unsigned short* __restrict__ Kp, int kstride,
                                               const unsigned short* __restrict__ Vt, int spad,
                                               unsigned short* __restrict__ Op, int ostride,
                                               int sq, int sk, float scale) {
    __shared__ __attribute__((aligned(16))) short Ks[64 * 104];  // [64 k][96+8 pad]
    __shared__ __attribute__((aligned(16))) short Vs[80 * 72];   // [80 d][64+8 pad]
    __shared__ __attribute__((aligned(16))) short Ps[64 * 72];   // [64 q][64+8 pad]

    const int t = threadIdx.x;
    const int lane = t & 63;
    const int w = t >> 6;
    const int fm = lane & 15;
    const int quad = lane >> 4;
    const int b = blockIdx.z, h = blockIdx.y;
    const int q0 = blockIdx.x * 64;

    // Q fragments (B-operand of S^T mfma; same lane map as A): q = w*16+fm
    bf16x8 qf[3];
    {
        const unsigned short* qbase =
            Qp + (size_t)(b * sq + q0 + w * 16 + fm) * qstride + h * DH;
        qf[0] = *(const bf16x8*)(qbase + quad * 8);
        qf[1] = *(const bf16x8*)(qbase + 32 + quad * 8);
        bf16x8 z = {0, 0, 0, 0, 0, 0, 0, 0};
        qf[2] = (quad < 2) ? *(const bf16x8*)(qbase + 64 + quad * 8) : z;
    }

    // per-lane softmax state for q = w*16+fm (replicated across quads)
    float mrow = -1e30f, lrow = 0.f;
    floatx4 oacc[5];
#pragma unroll
    for (int d = 0; d < 5; ++d) oacc[d] = (floatx4){0.f, 0.f, 0.f, 0.f};

    const int nkt = (sk + 63) >> 6;
    for (int kt = 0; kt < nkt; ++kt) {
        __syncthreads();  // prior iter's LDS readers done
        // ---- stage K tile [64][96] (zero-pad cols 80..95, mask rows>=sk) ----
        {
            const int tr = t >> 2, tc = t & 3;
            const int kr = kt * 64 + tr;
            const bool ok = kr < sk;
            const unsigned short* krow = Kp + (size_t)(b * sk + kr) * kstride + h * DH;
#pragma unroll
            for (int i = 0; i < 5; ++i) {
                const int col = tc * 4 + i * 16;
                ushort4 v = make_ushort4(0, 0, 0, 0);
                if (ok) v = *(const ushort4*)(krow + col);
                *(ushort4*)(Ks + tr * 104 + col) = v;
            }
            *(ushort4*)(Ks + tr * 104 + 80 + tc * 4) = make_ushort4(0, 0, 0, 0);
        }
        // ---- stage V^T tile [80][64] ----
        {
            const unsigned short* vbase = Vt + ((size_t)(b * 8 + h) * 80) * spad + kt * 64;
#pragma unroll
            for (int i = 0; i < 5; ++i) {
                const int lin = t + i * 256;       // 0..1279
                const int row = lin >> 4;          // 0..79
                const int colq = (lin & 15) * 4;   // 0..60
                ushort4 v = *(const ushort4*)(vbase + (size_t)row * spad + colq);
                *(ushort4*)(Vs + row * 72 + colq) = v;
            }
        }
        __syncthreads();

        // ---- S^T = K Q^T: D[k][q], col=q=fm, row(local k)=quad*4+r (+j*16) --
        floatx4 sacc[4];
#pragma unroll
        for (int j = 0; j < 4; ++j) sacc[j] = (floatx4){0.f, 0.f, 0.f, 0.f};
#pragma unroll
        for (int c = 0; c < 3; ++c) {
#pragma unroll
            for (int j = 0; j < 4; ++j) {
                bf16x8 kf = *(const bf16x8*)(Ks + (j * 16 + fm) * 104 + c * 32 + quad * 8);
                sacc[j] = __builtin_amdgcn_mfma_f32_16x16x32_bf16(kf, qf[c], sacc[j], 0, 0, 0);
            }
        }

        // ---- online softmax: row (q=fm) lives in-lane across j,r + quads ----
        float p[4][4];
#pragma unroll
        for (int j = 0; j < 4; ++j)
#pragma unroll
            for (int r = 0; r < 4; ++r) {
                const int kk = kt * 64 + j * 16 + quad * 4 + r;
                p[j][r] = (kk >= sk) ? -1e30f : sacc[j][r] * scale;
            }
        float mx = p[0][0];
#pragma unroll
        for (int j = 0; j < 4; ++j)
#pragma unroll
            for (int r = 0; r < 4; ++r) mx = fmaxf(mx, p[j][r]);
        mx = fmaxf(mx, __shfl_xor(mx, 16));
        mx = fmaxf(mx, __shfl_xor(mx, 32));
        const float mn = fmaxf(mrow, mx);
        const float alpha = __expf(mrow - mn);
        float rs = 0.f;
#pragma unroll
        for (int j = 0; j < 4; ++j)
#pragma unroll
            for (int r = 0; r < 4; ++r) { p[j][r] = __expf(p[j][r] - mn); rs += p[j][r]; }
        rs += __shfl_xor(rs, 16);
        rs += __shfl_xor(rs, 32);
        lrow = lrow * alpha + rs;
        mrow = mn;

        // alpha for O rows (q-local = quad*4+r) from lanes 0..15
        float al[4];
#pragma unroll
        for (int r = 0; r < 4; ++r) al[r] = __shfl(alpha, quad * 4 + r);
#pragma unroll
        for (int d = 0; d < 5; ++d)
#pragma unroll
            for (int r = 0; r < 4; ++r) oacc[d][r] *= al[r];

        // ---- P^T (C-layout [k][q]) -> Ps[q][k]: 4 consecutive k per lane ----
#pragma unroll
        for (int j = 0; j < 4; ++j) {
            ushort4 pk;
            pk.x = f2bf(p[j][0]); pk.y = f2bf(p[j][1]);
            pk.z = f2bf(p[j][2]); pk.w = f2bf(p[j][3]);
            *(ushort4*)(Ps + (w * 16 + fm) * 72 + j * 16 + quad * 4) = pk;
        }
        __syncthreads();

        // ---- O += P V  (A=P[q][k], B=V^T[k][d] -> D[q][d], col=d=fm) --------
        bf16x8 pf0 = *(const bf16x8*)(Ps + (w * 16 + fm) * 72 + quad * 8);
        bf16x8 pf1 = *(const bf16x8*)(Ps + (w * 16 + fm) * 72 + 32 + quad * 8);
#pragma unroll
        for (int d = 0; d < 5; ++d) {
            bf16x8 vf0 = *(const bf16x8*)(Vs + (d * 16 + fm) * 72 + quad * 8);
            bf16x8 vf1 = *(const bf16x8*)(Vs + (d * 16 + fm) * 72 + 32 + quad * 8);
            oacc[d] = __builtin_amdgcn_mfma_f32_16x16x32_bf16(pf0, vf0, oacc[d], 0, 0, 0);
            oacc[d] = __builtin_amdgcn_mfma_f32_16x16x32_bf16(pf1, vf1, oacc[d], 0, 0, 0);
        }
    }

    // ---- epilogue: O / l (l fetched per O-row from lanes 0..15) ----
    unsigned short* obase = Op + (size_t)(b * sq + q0 + w * 16) * ostride + h * DH;
#pragma unroll
    for (int r = 0; r < 4; ++r) {
        const float lr = __shfl(lrow, quad * 4 + r);
        const float inv = 1.f / lr;
#pragma unroll
        for (int d = 0; d < 5; ++d)
            obase[(size_t)(quad * 4 + r) * ostride + d * 16 + fm] = f2bf(oacc[d][r] * inv);
    }
}

// ---------------------------------------------------------------------------
extern "C" void kernel_launch(void* const* d_in, const int* in_sizes, int n_in,
                              void* d_out, int out_size, void* d_ws, size_t ws_size,
                              hipStream_t stream) {
    const float* x        = (const float*)d_in[0];
    const float* ctx      = (const float*)d_in[1];
    const float* gn_s     = (const float*)d_in[2];
    const float* gn_b     = (const float*)d_in[3];
    const float* conv1_w  = (const float*)d_in[4];
    const float* conv1_b  = (const float*)d_in[5];
    const float* ln1_s    = (const float*)d_in[6];
    const float* ln1_b    = (const float*)d_in[7];
    const float* sa_in_w  = (const float*)d_in[8];
    const float* sa_out_w = (const float*)d_in[9];
    const float* sa_out_b = (const float*)d_in[10];
    const float* ln2_s    = (const float*)d_in[11];
    const float* ln2_b    = (const float*)d_in[12];
    const float* ca_q_w   = (const float*)d_in[13];
    const float* ca_k_w   = (const float*)d_in[14];
    const float* ca_v_w   = (const float*)d_in[15];
    const float* ca_out_w = (const float*)d_in[16];
    const float* ca_out_b = (const float*)d_in[17];
    const float* ln3_s    = (const float*)d_in[18];
    const float* ln3_b    = (const float*)d_in[19];
    const float* lin1_w   = (const float*)d_in[20];
    const float* lin1_b   = (const float*)d_in[21];
    const float* lin2_w   = (const float*)d_in[22];
    const float* lin2_b   = (const float*)d_in[23];
    const float* co_w     = (const float*)d_in[24];
    const float* co_b     = (const float*)d_in[25];

    float* out = (float*)d_out;       // doubles as x_seq (fp32 residual stream)
    float* ws = (float*)d_ws;
    float* x_seq = out;

    // ws layout (float offsets)
    unsigned short* qk_b  = (unsigned short*)ws;               // [8192][1280] self QK; later cross q; later bf16 mirror
    unsigned short* h_b   = (unsigned short*)(ws + 5242880);   // [8192][2560] GeGLU out
    unsigned short* abuf  = (unsigned short*)(ws + 15728640);  // [8192][640] LN/attn buf
    unsigned short* kv0   = (unsigned short*)(ws + 18350080);  // [640][640] cross K
    unsigned short* vT_s  = (unsigned short*)(ws + 18554880);  // [64*80][1024] self V^T
    unsigned short* vT_c  = (unsigned short*)(ws + 21176320);  // [64*80][128] cross V^T
    unsigned short* ctx_b = (unsigned short*)(ws + 21504000);  // [640][512]
    size_t woff = 21667840;
    unsigned short* sa_in_wb  = (unsigned short*)(ws + woff); woff += 614400;
    unsigned short* sa_out_wb = (unsigned short*)(ws + woff); woff += 204800;
    unsigned short* ca_q_wb   = (unsigned short*)(ws + woff); woff += 204800;
    unsigned short* ca_k_wb   = (unsigned short*)(ws + woff); woff += 163840;
    unsigned short* ca_v_wb   = (unsigned short*)(ws + woff); woff += 163840;
    unsigned short* ca_out_wb = (unsigned short*)(ws + woff); woff += 204800;
    unsigned short* lin1_wb   = (unsigned short*)(ws + woff); woff += 1638400;
    unsigned short* lin2_wb   = (unsigned short*)(ws + woff); woff += 819200;
    unsigned short* conv1_wb  = (unsigned short*)(ws + woff); woff += 204800;
    unsigned short* co_wb     = (unsigned short*)(ws + woff); woff += 204800;
    float* stats = ws + woff;

    const float scale = 0.11180339887498949f;  // 1/sqrt(80)

    // ---- weight prep: 2 launches ----
    prep_tr_k<<<7840, 256, 0, stream>>>(sa_in_w, sa_in_wb, sa_out_w, sa_out_wb,
                                        ca_q_w, ca_q_wb, ca_k_w, ca_k_wb,
                                        ca_v_w, ca_v_wb, ca_out_w, ca_out_wb,
                                        lin1_w, lin1_wb, lin2_w, lin2_wb);
    prep_ew_k<<<5760, 256, 0, stream>>>(conv1_w, conv1_wb, co_w, co_wb, ctx, ctx_b,
                                        (unsigned int*)vT_c);

    // ---- 1. GroupNorm + transpose (bf16) ----
    gn_stats_k<<<256, 256, 0, stream>>>(x, stats);
    gn_apply_t_k<<<dim3(32, 20, 8), 256, 0, stream>>>(x, stats, gn_s, gn_b, abuf);
    // ---- 2. conv1 -> x_seq fp32 ----
    bgemm_k<EPI_OUT, float><<<dim3(64, 5), 256, 0, stream>>>(abuf, 640, conv1_wb, 640, conv1_b, x_seq, 640, nullptr, nullptr, 8192, 640, 640);
    // ---- 3. LN1 + QKV(+V^T) + self-attn + out-proj (+res) ----
    ln_k<<<2048, 256, 0, stream>>>(x_seq, ln1_s, ln1_b, abuf);
    bgemm_k<EPI_QKV, unsigned short><<<dim3(64, 15), 256, 0, stream>>>(abuf, 640, sa_in_wb, 640, nullptr, qk_b, 1280, nullptr, vT_s, 8192, 1920, 640);
    mattn_k<<<dim3(16, 8, 8), 256, 0, stream>>>(qk_b, 1280, qk_b + 640, 1280, vT_s, 1024, abuf, 640, 1024, 1024, scale);
    bgemm_k<EPI_RES, float><<<dim3(64, 5), 256, 0, stream>>>(abuf, 640, sa_out_wb, 640, sa_out_b, x_seq, 640, nullptr, nullptr, 8192, 640, 640);
    // ---- 4. LN2 + cross-attn (+res) ----
    ln_k<<<2048, 256, 0, stream>>>(x_seq, ln2_s, ln2_b, abuf);
    cross_gemms_k<<<370, 256, 0, stream>>>(abuf, ctx_b, ca_q_wb, ca_k_wb, ca_v_wb,
                                           qk_b, kv0, vT_c);
    mattn_k<<<dim3(16, 8, 8), 256, 0, stream>>>(qk_b, 640, kv0, 640, vT_c, 128, abuf, 640, 1024, 77, scale);
    bgemm_k<EPI_RES, float><<<dim3(64, 5), 256, 0, stream>>>(abuf, 640, ca_out_wb, 640, ca_out_b, x_seq, 640, nullptr, nullptr, 8192, 640, 640);
    // ---- 5. LN3 + fused GeGLU FFN (+res, bf16 mirror) ----
    ln_k<<<2048, 256, 0, stream>>>(x_seq, ln3_s, ln3_b, abuf);
    geglu_k<<<dim3(64, 20), 256, 0, stream>>>(abuf, lin1_wb, lin1_wb + (size_t)2560 * 640, lin1_b, h_b);
    bgemm_k<EPI_RES_BF, float><<<dim3(64, 5), 256, 0, stream>>>(h_b, 2560, lin2_wb, 2560, lin2_b, x_seq, 640, nullptr, qk_b, 8192, 640, 2560);
    // ---- 6. final conv1x1 + long residual (transposed write) ----
    bgemm_k<EPI_CONVT, float><<<dim3(64, 5), 256, 0, stream>>>(qk_b, 640, co_wb, 640, co_b, out, 0, x, nullptr, 8192, 640, 640);
}